// Round 1
// baseline (748.871 us; speedup 1.0000x reference)
//
#include <hip/hip_runtime.h>

#define N_NODES 50000
#define N_EDGES 800000
#define BN_EPS 1e-5f

// ---------------- degree / dinv ----------------
__global__ __launch_bounds__(256) void deg_kernel(const int* __restrict__ src,
                                                  const int* __restrict__ dst,
                                                  float* __restrict__ deg) {
    int e = blockIdx.x * 256 + threadIdx.x;
    if (e < N_EDGES) {
        int s = src[e], d = dst[e];
        if (s != d) atomicAdd(&deg[d], 1.0f);
    }
}

__global__ __launch_bounds__(256) void dinv_kernel(float* __restrict__ deg_dinv) {
    int i = blockIdx.x * 256 + threadIdx.x;
    if (i < N_NODES) deg_dinv[i] = rsqrtf(deg_dinv[i] + 1.0f);
}

// ---------------- GEMM1: H = X @ W1 + b1  (N x 128)(128 x 128) ----------------
// block tile 128x128, BK=16, 256 threads, 8x8 register tile
__global__ __launch_bounds__(256) void gemm1_kernel(const float* __restrict__ X,
                                                    const float* __restrict__ W,
                                                    const float* __restrict__ bias,
                                                    float* __restrict__ H) {
    __shared__ float Ast[16][128];  // A chunk, transposed (k-major)
    __shared__ float Bs[16][128];
    const int t = threadIdx.x;
    const int rowBase = blockIdx.x * 128;
    const int rg = t >> 4, cg = t & 15;
    const int lr = t >> 1, lcp = (t & 1) * 2;

    float acc[8][8];
#pragma unroll
    for (int i = 0; i < 8; ++i)
#pragma unroll
        for (int j = 0; j < 8; ++j) acc[i][j] = 0.f;

    for (int kc = 0; kc < 128; kc += 16) {
        // A tile load (guarded), store transposed
        const int arow = rowBase + lr;
#pragma unroll
        for (int i = 0; i < 2; ++i) {
            const int col4 = lcp + i;
            float4 v = make_float4(0.f, 0.f, 0.f, 0.f);
            if (arow < N_NODES)
                v = *(const float4*)&X[arow * 128 + kc + col4 * 4];
            Ast[col4 * 4 + 0][lr] = v.x;
            Ast[col4 * 4 + 1][lr] = v.y;
            Ast[col4 * 4 + 2][lr] = v.z;
            Ast[col4 * 4 + 3][lr] = v.w;
        }
        // B tile load
        {
            const int kr = t >> 4, c4 = t & 15;
#pragma unroll
            for (int i = 0; i < 2; ++i) {
                const int cc = c4 + i * 16;
                *(float4*)&Bs[kr][cc * 4] = *(const float4*)&W[(kc + kr) * 128 + cc * 4];
            }
        }
        __syncthreads();
#pragma unroll
        for (int kk = 0; kk < 16; ++kk) {
            float4 a0 = *(const float4*)&Ast[kk][rg * 8];
            float4 a1 = *(const float4*)&Ast[kk][rg * 8 + 4];
            float4 b0 = *(const float4*)&Bs[kk][cg * 8];
            float4 b1 = *(const float4*)&Bs[kk][cg * 8 + 4];
            float a[8] = {a0.x, a0.y, a0.z, a0.w, a1.x, a1.y, a1.z, a1.w};
            float b[8] = {b0.x, b0.y, b0.z, b0.w, b1.x, b1.y, b1.z, b1.w};
#pragma unroll
            for (int i = 0; i < 8; ++i)
#pragma unroll
                for (int j = 0; j < 8; ++j) acc[i][j] += a[i] * b[j];
        }
        __syncthreads();
    }

    float4 bb0 = *(const float4*)&bias[cg * 8];
    float4 bb1 = *(const float4*)&bias[cg * 8 + 4];
#pragma unroll
    for (int i = 0; i < 8; ++i) {
        const int row = rowBase + rg * 8 + i;
        if (row < N_NODES) {
            float4 o0 = make_float4(acc[i][0] + bb0.x, acc[i][1] + bb0.y,
                                    acc[i][2] + bb0.z, acc[i][3] + bb0.w);
            float4 o1 = make_float4(acc[i][4] + bb1.x, acc[i][5] + bb1.y,
                                    acc[i][6] + bb1.z, acc[i][7] + bb1.w);
            *(float4*)&H[row * 128 + cg * 8] = o0;
            *(float4*)&H[row * 128 + cg * 8 + 4] = o1;
        }
    }
}

// ---------------- GEMM2: H2 = relu(bn(H1agg)) @ W2 + b2  (N x 128)(128 x 64) ----
// block tile 128x64, BK=16, 256 threads, 8x4 register tile; BN+ReLU fused at A load
__global__ __launch_bounds__(256) void gemm2_kernel(const float* __restrict__ Hin,
                                                    const float* __restrict__ W,
                                                    const float* __restrict__ bias,
                                                    const float* __restrict__ scale,
                                                    const float* __restrict__ shift,
                                                    float* __restrict__ Hout) {
    __shared__ float Ast[16][128];
    __shared__ float Bs[16][64];
    const int t = threadIdx.x;
    const int rowBase = blockIdx.x * 128;
    const int rg = t >> 4, cg = t & 15;
    const int lr = t >> 1, lcp = (t & 1) * 2;

    float acc[8][4];
#pragma unroll
    for (int i = 0; i < 8; ++i)
#pragma unroll
        for (int j = 0; j < 4; ++j) acc[i][j] = 0.f;

    for (int kc = 0; kc < 128; kc += 16) {
        const int arow = rowBase + lr;
#pragma unroll
        for (int i = 0; i < 2; ++i) {
            const int col4 = lcp + i;
            const int kg = kc + col4 * 4;
            float4 v = make_float4(0.f, 0.f, 0.f, 0.f);
            if (arow < N_NODES) {
                float4 h = *(const float4*)&Hin[arow * 128 + kg];
                float4 sc = *(const float4*)&scale[kg];
                float4 sh = *(const float4*)&shift[kg];
                v.x = fmaxf(0.f, h.x * sc.x + sh.x);
                v.y = fmaxf(0.f, h.y * sc.y + sh.y);
                v.z = fmaxf(0.f, h.z * sc.z + sh.z);
                v.w = fmaxf(0.f, h.w * sc.w + sh.w);
            }
            Ast[col4 * 4 + 0][lr] = v.x;
            Ast[col4 * 4 + 1][lr] = v.y;
            Ast[col4 * 4 + 2][lr] = v.z;
            Ast[col4 * 4 + 3][lr] = v.w;
        }
        // B tile: 16x64 floats = exactly one float4 per thread
        *(float4*)&Bs[t >> 4][(t & 15) * 4] =
            *(const float4*)&W[(kc + (t >> 4)) * 64 + (t & 15) * 4];
        __syncthreads();
#pragma unroll
        for (int kk = 0; kk < 16; ++kk) {
            float4 a0 = *(const float4*)&Ast[kk][rg * 8];
            float4 a1 = *(const float4*)&Ast[kk][rg * 8 + 4];
            float4 b0 = *(const float4*)&Bs[kk][cg * 4];
            float a[8] = {a0.x, a0.y, a0.z, a0.w, a1.x, a1.y, a1.z, a1.w};
            float b[4] = {b0.x, b0.y, b0.z, b0.w};
#pragma unroll
            for (int i = 0; i < 8; ++i)
#pragma unroll
                for (int j = 0; j < 4; ++j) acc[i][j] += a[i] * b[j];
        }
        __syncthreads();
    }

    float4 bb = *(const float4*)&bias[cg * 4];
#pragma unroll
    for (int i = 0; i < 8; ++i) {
        const int row = rowBase + rg * 8 + i;
        if (row < N_NODES) {
            float4 o = make_float4(acc[i][0] + bb.x, acc[i][1] + bb.y,
                                   acc[i][2] + bb.z, acc[i][3] + bb.w);
            *(float4*)&Hout[row * 64 + cg * 4] = o;
        }
    }
}

// ---------------- out[i][c] = dinv[i]^2 * H[i][c]  (self-loop init) ----------------
template <int C>
__global__ __launch_bounds__(256) void self_init_kernel(const float* __restrict__ H,
                                                        const float* __restrict__ dinv,
                                                        float* __restrict__ out) {
    int idx = blockIdx.x * 256 + threadIdx.x;
    if (idx < N_NODES * C) {
        int i = idx / C;  // C is a power of two -> shift
        float dv = dinv[i];
        out[idx] = dv * dv * H[idx];
    }
}

// ---------------- edge-parallel SpMM scatter: out[src] += w * H[dst] ----------------
__global__ __launch_bounds__(256) void spmm_edge128_kernel(const int* __restrict__ src,
                                                           const int* __restrict__ dst,
                                                           const float* __restrict__ dinv,
                                                           const float* __restrict__ H,
                                                           float* __restrict__ out) {
    int e = blockIdx.x * 2 + (threadIdx.x >> 7);
    int c = threadIdx.x & 127;
    int s = src[e], d = dst[e];
    if (s == d) return;
    float w = dinv[s] * dinv[d];
    atomicAdd(&out[s * 128 + c], w * H[d * 128 + c]);
}

__global__ __launch_bounds__(256) void spmm_edge64_kernel(const int* __restrict__ src,
                                                          const int* __restrict__ dst,
                                                          const float* __restrict__ dinv,
                                                          const float* __restrict__ H,
                                                          float* __restrict__ out) {
    int e = blockIdx.x * 4 + (threadIdx.x >> 6);
    int c = threadIdx.x & 63;
    int s = src[e], d = dst[e];
    if (s == d) return;
    float w = dinv[s] * dinv[d];
    atomicAdd(&out[s * 64 + c], w * H[d * 64 + c]);
}

// ---------------- BN statistics ----------------
__global__ __launch_bounds__(256) void bn_stats_kernel(const float* __restrict__ H,
                                                       float* __restrict__ sum,
                                                       float* __restrict__ sumsq) {
    int c = threadIdx.x & 127;
    int half = threadIdx.x >> 7;
    float s = 0.f, q = 0.f;
    for (int r = blockIdx.x * 2 + half; r < N_NODES; r += 512) {
        float v = H[r * 128 + c];
        s += v;
        q += v * v;
    }
    __shared__ float ls[256], lq[256];
    ls[threadIdx.x] = s;
    lq[threadIdx.x] = q;
    __syncthreads();
    if (half == 0) {
        atomicAdd(&sum[c], ls[c] + ls[c + 128]);
        atomicAdd(&sumsq[c], lq[c] + lq[c + 128]);
    }
}

__global__ void bn_finalize_kernel(const float* __restrict__ sum,
                                   const float* __restrict__ sumsq,
                                   const float* __restrict__ gamma,
                                   const float* __restrict__ beta,
                                   float* __restrict__ scale,
                                   float* __restrict__ shift) {
    int c = threadIdx.x;
    if (c < 128) {
        float mean = sum[c] * (1.0f / N_NODES);
        float var = sumsq[c] * (1.0f / N_NODES) - mean * mean;
        float sc = gamma[c] * rsqrtf(var + BN_EPS);
        scale[c] = sc;
        shift[c] = beta[c] - mean * sc;
    }
}

extern "C" void kernel_launch(void* const* d_in, const int* in_sizes, int n_in,
                              void* d_out, int out_size, void* d_ws, size_t ws_size,
                              hipStream_t stream) {
    const float* x     = (const float*)d_in[0];
    const int*   ei    = (const int*)d_in[1];
    const float* W1    = (const float*)d_in[2];
    const float* b1    = (const float*)d_in[3];
    const float* gamma = (const float*)d_in[4];
    const float* beta  = (const float*)d_in[5];
    const float* W2    = (const float*)d_in[6];
    const float* b2    = (const float*)d_in[7];
    float* out = (float*)d_out;
    const int* src = ei;             // edge_index[0]
    const int* dst = ei + N_EDGES;   // edge_index[1]

    float* ws    = (float*)d_ws;
    float* dinv  = ws;                       // N_NODES (padded region 51200)
    float* stats = ws + 51200;               // sum,sumsq,scale,shift: 4*128
    float* h1    = ws + 51200 + 512;         // N*128
    float* h1agg = h1 + N_NODES * 128;       // N*128
    float* h2    = h1;                       // alias: h1 dead after spmm1
    float* sum   = stats;
    float* sumsq = stats + 128;
    float* scale = stats + 256;
    float* shift = stats + 384;

    hipMemsetAsync(dinv, 0, N_NODES * sizeof(float), stream);
    hipMemsetAsync(stats, 0, 256 * sizeof(float), stream);

    deg_kernel<<<(N_EDGES + 255) / 256, 256, 0, stream>>>(src, dst, dinv);
    dinv_kernel<<<(N_NODES + 255) / 256, 256, 0, stream>>>(dinv);

    gemm1_kernel<<<(N_NODES + 127) / 128, 256, 0, stream>>>(x, W1, b1, h1);

    self_init_kernel<128><<<(N_NODES * 128 + 255) / 256, 256, 0, stream>>>(h1, dinv, h1agg);
    spmm_edge128_kernel<<<N_EDGES / 2, 256, 0, stream>>>(src, dst, dinv, h1, h1agg);

    bn_stats_kernel<<<256, 256, 0, stream>>>(h1agg, sum, sumsq);
    bn_finalize_kernel<<<1, 128, 0, stream>>>(sum, sumsq, gamma, beta, scale, shift);

    gemm2_kernel<<<(N_NODES + 127) / 128, 256, 0, stream>>>(h1agg, W2, b2, scale, shift, h2);

    self_init_kernel<64><<<(N_NODES * 64 + 255) / 256, 256, 0, stream>>>(h2, dinv, out);
    spmm_edge64_kernel<<<N_EDGES / 4, 256, 0, stream>>>(src, dst, dinv, h2, out);
}

// Round 2
// 518.792 us; speedup vs baseline: 1.4435x; 1.4435x over previous
//
#include <hip/hip_runtime.h>

#define N_NODES 50000
#define N_EDGES 800000
#define BN_EPS 1e-5f
#define NPAD 50176          // N_NODES padded to 98*512
#define SCAN_BLOCKS 98      // 98*512 = 50176

// ---------------- edge counting: degN over dst (normalization), rowcnt over src (CSR) --
__global__ __launch_bounds__(256) void count_kernel(const int* __restrict__ src,
                                                    const int* __restrict__ dst,
                                                    int* __restrict__ degN,
                                                    int* __restrict__ rowcnt) {
    int e = blockIdx.x * 256 + threadIdx.x;
    if (e < N_EDGES) {
        int s = src[e], d = dst[e];
        if (s != d) {
            atomicAdd(&degN[d], 1);
            atomicAdd(&rowcnt[s], 1);
        }
    }
}

__global__ __launch_bounds__(256) void dinv_kernel(const int* __restrict__ degN,
                                                   float* __restrict__ dinv) {
    int i = blockIdx.x * 256 + threadIdx.x;
    if (i < N_NODES) dinv[i] = rsqrtf((float)degN[i] + 1.0f);
}

// ---------------- exclusive scan of rowcnt -> rowptr (3 kernels) ----------------
// scan1: per-block inclusive scan (512 elems), write inclusive to rowptr, block sum to psum
__global__ __launch_bounds__(512) void scan1_kernel(const int* __restrict__ rowcnt,
                                                    int* __restrict__ rowptr,
                                                    int* __restrict__ psum) {
    __shared__ int buf[512];
    int t = threadIdx.x;
    int g = blockIdx.x * 512 + t;
    buf[t] = rowcnt[g];
    __syncthreads();
#pragma unroll
    for (int off = 1; off < 512; off <<= 1) {
        int x = (t >= off) ? buf[t - off] : 0;
        __syncthreads();
        buf[t] += x;
        __syncthreads();
    }
    rowptr[g] = buf[t];
    if (t == 511) psum[blockIdx.x] = buf[511];
}

// scan2: exclusive scan of the 98 block sums (serial, tiny)
__global__ void scan2_kernel(int* __restrict__ psum) {
    if (threadIdx.x == 0) {
        int acc = 0;
        for (int i = 0; i < SCAN_BLOCKS; ++i) {
            int v = psum[i];
            psum[i] = acc;
            acc += v;
        }
    }
}

// scan3: rowptr[i] = inclusive[i] - rowcnt[i] + psum[b]  (exclusive), also init cursor
__global__ __launch_bounds__(512) void scan3_kernel(const int* __restrict__ rowcnt,
                                                    int* __restrict__ rowptr,
                                                    const int* __restrict__ psum,
                                                    int* __restrict__ cursor) {
    int t = threadIdx.x;
    int g = blockIdx.x * 512 + t;
    int v = rowptr[g] - rowcnt[g] + psum[blockIdx.x];
    rowptr[g] = v;
    cursor[g] = v;
}

// ---------------- fill CSR column indices ----------------
__global__ __launch_bounds__(256) void fill_kernel(const int* __restrict__ src,
                                                   const int* __restrict__ dst,
                                                   int* __restrict__ cursor,
                                                   int* __restrict__ ecol) {
    int e = blockIdx.x * 256 + threadIdx.x;
    if (e < N_EDGES) {
        int s = src[e], d = dst[e];
        if (s != d) {
            int pos = atomicAdd(&cursor[s], 1);
            ecol[pos] = d;
        }
    }
}

// ---------------- GEMM1: H = X @ W1 + b1  (N x 128)(128 x 128) ----------------
__global__ __launch_bounds__(256) void gemm1_kernel(const float* __restrict__ X,
                                                    const float* __restrict__ W,
                                                    const float* __restrict__ bias,
                                                    float* __restrict__ H) {
    __shared__ float Ast[16][128];
    __shared__ float Bs[16][128];
    const int t = threadIdx.x;
    const int rowBase = blockIdx.x * 128;
    const int rg = t >> 4, cg = t & 15;
    const int lr = t >> 1, lcp = (t & 1) * 2;

    float acc[8][8];
#pragma unroll
    for (int i = 0; i < 8; ++i)
#pragma unroll
        for (int j = 0; j < 8; ++j) acc[i][j] = 0.f;

    for (int kc = 0; kc < 128; kc += 16) {
        const int arow = rowBase + lr;
#pragma unroll
        for (int i = 0; i < 2; ++i) {
            const int col4 = lcp + i;
            float4 v = make_float4(0.f, 0.f, 0.f, 0.f);
            if (arow < N_NODES)
                v = *(const float4*)&X[arow * 128 + kc + col4 * 4];
            Ast[col4 * 4 + 0][lr] = v.x;
            Ast[col4 * 4 + 1][lr] = v.y;
            Ast[col4 * 4 + 2][lr] = v.z;
            Ast[col4 * 4 + 3][lr] = v.w;
        }
        {
            const int kr = t >> 4, c4 = t & 15;
#pragma unroll
            for (int i = 0; i < 2; ++i) {
                const int cc = c4 + i * 16;
                *(float4*)&Bs[kr][cc * 4] = *(const float4*)&W[(kc + kr) * 128 + cc * 4];
            }
        }
        __syncthreads();
#pragma unroll
        for (int kk = 0; kk < 16; ++kk) {
            float4 a0 = *(const float4*)&Ast[kk][rg * 8];
            float4 a1 = *(const float4*)&Ast[kk][rg * 8 + 4];
            float4 b0 = *(const float4*)&Bs[kk][cg * 8];
            float4 b1 = *(const float4*)&Bs[kk][cg * 8 + 4];
            float a[8] = {a0.x, a0.y, a0.z, a0.w, a1.x, a1.y, a1.z, a1.w};
            float b[8] = {b0.x, b0.y, b0.z, b0.w, b1.x, b1.y, b1.z, b1.w};
#pragma unroll
            for (int i = 0; i < 8; ++i)
#pragma unroll
                for (int j = 0; j < 8; ++j) acc[i][j] += a[i] * b[j];
        }
        __syncthreads();
    }

    float4 bb0 = *(const float4*)&bias[cg * 8];
    float4 bb1 = *(const float4*)&bias[cg * 8 + 4];
#pragma unroll
    for (int i = 0; i < 8; ++i) {
        const int row = rowBase + rg * 8 + i;
        if (row < N_NODES) {
            float4 o0 = make_float4(acc[i][0] + bb0.x, acc[i][1] + bb0.y,
                                    acc[i][2] + bb0.z, acc[i][3] + bb0.w);
            float4 o1 = make_float4(acc[i][4] + bb1.x, acc[i][5] + bb1.y,
                                    acc[i][6] + bb1.z, acc[i][7] + bb1.w);
            *(float4*)&H[row * 128 + cg * 8] = o0;
            *(float4*)&H[row * 128 + cg * 8 + 4] = o1;
        }
    }
}

// ---------------- GEMM2: H2 = relu(bn(H1agg)) @ W2 + b2 ----------------
__global__ __launch_bounds__(256) void gemm2_kernel(const float* __restrict__ Hin,
                                                    const float* __restrict__ W,
                                                    const float* __restrict__ bias,
                                                    const float* __restrict__ scale,
                                                    const float* __restrict__ shift,
                                                    float* __restrict__ Hout) {
    __shared__ float Ast[16][128];
    __shared__ float Bs[16][64];
    const int t = threadIdx.x;
    const int rowBase = blockIdx.x * 128;
    const int rg = t >> 4, cg = t & 15;
    const int lr = t >> 1, lcp = (t & 1) * 2;

    float acc[8][4];
#pragma unroll
    for (int i = 0; i < 8; ++i)
#pragma unroll
        for (int j = 0; j < 4; ++j) acc[i][j] = 0.f;

    for (int kc = 0; kc < 128; kc += 16) {
        const int arow = rowBase + lr;
#pragma unroll
        for (int i = 0; i < 2; ++i) {
            const int col4 = lcp + i;
            const int kg = kc + col4 * 4;
            float4 v = make_float4(0.f, 0.f, 0.f, 0.f);
            if (arow < N_NODES) {
                float4 h = *(const float4*)&Hin[arow * 128 + kg];
                float4 sc = *(const float4*)&scale[kg];
                float4 sh = *(const float4*)&shift[kg];
                v.x = fmaxf(0.f, h.x * sc.x + sh.x);
                v.y = fmaxf(0.f, h.y * sc.y + sh.y);
                v.z = fmaxf(0.f, h.z * sc.z + sh.z);
                v.w = fmaxf(0.f, h.w * sc.w + sh.w);
            }
            Ast[col4 * 4 + 0][lr] = v.x;
            Ast[col4 * 4 + 1][lr] = v.y;
            Ast[col4 * 4 + 2][lr] = v.z;
            Ast[col4 * 4 + 3][lr] = v.w;
        }
        *(float4*)&Bs[t >> 4][(t & 15) * 4] =
            *(const float4*)&W[(kc + (t >> 4)) * 64 + (t & 15) * 4];
        __syncthreads();
#pragma unroll
        for (int kk = 0; kk < 16; ++kk) {
            float4 a0 = *(const float4*)&Ast[kk][rg * 8];
            float4 a1 = *(const float4*)&Ast[kk][rg * 8 + 4];
            float4 b0 = *(const float4*)&Bs[kk][cg * 4];
            float a[8] = {a0.x, a0.y, a0.z, a0.w, a1.x, a1.y, a1.z, a1.w};
            float b[4] = {b0.x, b0.y, b0.z, b0.w};
#pragma unroll
            for (int i = 0; i < 8; ++i)
#pragma unroll
                for (int j = 0; j < 4; ++j) acc[i][j] += a[i] * b[j];
        }
        __syncthreads();
    }

    float4 bb = *(const float4*)&bias[cg * 4];
#pragma unroll
    for (int i = 0; i < 8; ++i) {
        const int row = rowBase + rg * 8 + i;
        if (row < N_NODES) {
            float4 o = make_float4(acc[i][0] + bb.x, acc[i][1] + bb.y,
                                   acc[i][2] + bb.z, acc[i][3] + bb.w);
            *(float4*)&Hout[row * 64 + cg * 4] = o;
        }
    }
}

// ---------------- CSR gather SpMM, C channels, self-loop folded in ----------------
// out[i][c] = dinv[i]^2*H[i][c] + sum_e dinv[i]*dinv[d]*H[d][c]
template <int C, int ROWS_PER_BLOCK>
__global__ __launch_bounds__(256) void spmm_gather_kernel(const int* __restrict__ rowptr,
                                                          const int* __restrict__ ecol,
                                                          const float* __restrict__ dinv,
                                                          const float* __restrict__ H,
                                                          float* __restrict__ out) {
    const int t = threadIdx.x;
    const int c = t & (C - 1);
    const int row = blockIdx.x * ROWS_PER_BLOCK + (t / C);
    if (row >= N_NODES) return;
    const float di = dinv[row];
    float acc = di * di * H[row * C + c];
    const int e0 = rowptr[row], e1 = rowptr[row + 1];
    for (int e = e0; e < e1; ++e) {
        int d = ecol[e];
        acc += di * dinv[d] * H[d * C + c];
    }
    out[row * C + c] = acc;
}

// ---------------- BN statistics ----------------
__global__ __launch_bounds__(256) void bn_stats_kernel(const float* __restrict__ H,
                                                       float* __restrict__ sum,
                                                       float* __restrict__ sumsq) {
    int c = threadIdx.x & 127;
    int half = threadIdx.x >> 7;
    float s = 0.f, q = 0.f;
    for (int r = blockIdx.x * 2 + half; r < N_NODES; r += 512) {
        float v = H[r * 128 + c];
        s += v;
        q += v * v;
    }
    __shared__ float ls[256], lq[256];
    ls[threadIdx.x] = s;
    lq[threadIdx.x] = q;
    __syncthreads();
    if (half == 0) {
        atomicAdd(&sum[c], ls[c] + ls[c + 128]);
        atomicAdd(&sumsq[c], lq[c] + lq[c + 128]);
    }
}

__global__ void bn_finalize_kernel(const float* __restrict__ sum,
                                   const float* __restrict__ sumsq,
                                   const float* __restrict__ gamma,
                                   const float* __restrict__ beta,
                                   float* __restrict__ scale,
                                   float* __restrict__ shift) {
    int c = threadIdx.x;
    if (c < 128) {
        float mean = sum[c] * (1.0f / N_NODES);
        float var = sumsq[c] * (1.0f / N_NODES) - mean * mean;
        float sc = gamma[c] * rsqrtf(var + BN_EPS);
        scale[c] = sc;
        shift[c] = beta[c] - mean * sc;
    }
}

extern "C" void kernel_launch(void* const* d_in, const int* in_sizes, int n_in,
                              void* d_out, int out_size, void* d_ws, size_t ws_size,
                              hipStream_t stream) {
    const float* x     = (const float*)d_in[0];
    const int*   ei    = (const int*)d_in[1];
    const float* W1    = (const float*)d_in[2];
    const float* b1    = (const float*)d_in[3];
    const float* gamma = (const float*)d_in[4];
    const float* beta  = (const float*)d_in[5];
    const float* W2    = (const float*)d_in[6];
    const float* b2    = (const float*)d_in[7];
    float* out = (float*)d_out;
    const int* src = ei;
    const int* dst = ei + N_EDGES;

    // workspace layout (4-byte units)
    float* ws     = (float*)d_ws;
    float* dinv   = ws;                          // [0, NPAD)
    float* stats  = ws + NPAD;                   // 512
    int*   degN   = (int*)(ws + NPAD + 512);     // NPAD
    int*   rowcnt = degN + NPAD;                 // NPAD
    int*   rowptr = rowcnt + NPAD;               // NPAD
    int*   cursor = rowptr + NPAD;               // NPAD
    int*   psum   = cursor + NPAD;               // 128
    int*   ecol   = psum + 128;                  // N_EDGES
    float* h1     = (float*)(ecol + N_EDGES);    // N*128
    float* h1agg  = h1 + N_NODES * 128;          // N*128
    float* h2     = h1;                          // alias (h1 dead after spmm1)
    float* sum    = stats;
    float* sumsq  = stats + 128;
    float* scale  = stats + 256;
    float* shift  = stats + 384;

    hipMemsetAsync(stats, 0, 512 * sizeof(float), stream);
    hipMemsetAsync(degN, 0, 2 * NPAD * sizeof(int), stream);  // degN + rowcnt

    count_kernel<<<(N_EDGES + 255) / 256, 256, 0, stream>>>(src, dst, degN, rowcnt);
    dinv_kernel<<<(N_NODES + 255) / 256, 256, 0, stream>>>(degN, dinv);

    scan1_kernel<<<SCAN_BLOCKS, 512, 0, stream>>>(rowcnt, rowptr, psum);
    scan2_kernel<<<1, 64, 0, stream>>>(psum);
    scan3_kernel<<<SCAN_BLOCKS, 512, 0, stream>>>(rowcnt, rowptr, psum, cursor);
    fill_kernel<<<(N_EDGES + 255) / 256, 256, 0, stream>>>(src, dst, cursor, ecol);

    gemm1_kernel<<<(N_NODES + 127) / 128, 256, 0, stream>>>(x, W1, b1, h1);

    spmm_gather_kernel<128, 2><<<(N_NODES + 1) / 2, 256, 0, stream>>>(rowptr, ecol, dinv, h1, h1agg);

    bn_stats_kernel<<<256, 256, 0, stream>>>(h1agg, sum, sumsq);
    bn_finalize_kernel<<<1, 128, 0, stream>>>(sum, sumsq, gamma, beta, scale, shift);

    gemm2_kernel<<<(N_NODES + 127) / 128, 256, 0, stream>>>(h1agg, W2, b2, scale, shift, h2);

    spmm_gather_kernel<64, 4><<<(N_NODES + 3) / 4, 256, 0, stream>>>(rowptr, ecol, dinv, h2, out);
}

// Round 3
// 354.793 us; speedup vs baseline: 2.1107x; 1.4622x over previous
//
#include <hip/hip_runtime.h>

#define N_NODES 50000
#define N_EDGES 800000
#define BN_EPS 1e-5f
#define NPAD 50176          // N_NODES padded to 98*512
#define SCAN_BLOCKS 98      // 98*512 = 50176

typedef unsigned int uint;

// ---- bf16 helpers (stored as packed pairs in uint) ----
__device__ __forceinline__ float bfl(uint u) { return __uint_as_float(u << 16); }
__device__ __forceinline__ float bfh(uint u) { return __uint_as_float(u & 0xffff0000u); }
__device__ __forceinline__ uint pack_bf2(float a, float b) {
    uint ua = __float_as_uint(a), ub = __float_as_uint(b);
    ua += 0x7fffu + ((ua >> 16) & 1u);   // RNE
    ub += 0x7fffu + ((ub >> 16) & 1u);
    return (ua >> 16) | (ub & 0xffff0000u);
}
__device__ __forceinline__ void acc8(float* a, uint4 h, float w) {
    a[0] += w * bfl(h.x); a[1] += w * bfh(h.x);
    a[2] += w * bfl(h.y); a[3] += w * bfh(h.y);
    a[4] += w * bfl(h.z); a[5] += w * bfh(h.z);
    a[6] += w * bfl(h.w); a[7] += w * bfh(h.w);
}

// ---------------- edge counting ----------------
__global__ __launch_bounds__(256) void count_kernel(const int* __restrict__ src,
                                                    const int* __restrict__ dst,
                                                    int* __restrict__ degN,
                                                    int* __restrict__ rowcnt) {
    int e = blockIdx.x * 256 + threadIdx.x;
    if (e < N_EDGES) {
        int s = src[e], d = dst[e];
        if (s != d) {
            atomicAdd(&degN[d], 1);
            atomicAdd(&rowcnt[s], 1);
        }
    }
}

__global__ __launch_bounds__(256) void dinv_kernel(const int* __restrict__ degN,
                                                   float* __restrict__ dinv) {
    int i = blockIdx.x * 256 + threadIdx.x;
    if (i < N_NODES) dinv[i] = rsqrtf((float)degN[i] + 1.0f);
}

// ---------------- exclusive scan of rowcnt -> rowptr ----------------
__global__ __launch_bounds__(512) void scan1_kernel(const int* __restrict__ rowcnt,
                                                    int* __restrict__ rowptr,
                                                    int* __restrict__ psum) {
    __shared__ int buf[512];
    int t = threadIdx.x;
    int g = blockIdx.x * 512 + t;
    buf[t] = rowcnt[g];
    __syncthreads();
#pragma unroll
    for (int off = 1; off < 512; off <<= 1) {
        int x = (t >= off) ? buf[t - off] : 0;
        __syncthreads();
        buf[t] += x;
        __syncthreads();
    }
    rowptr[g] = buf[t];
    if (t == 511) psum[blockIdx.x] = buf[511];
}

__global__ void scan2_kernel(int* __restrict__ psum) {
    if (threadIdx.x == 0) {
        int acc = 0;
        for (int i = 0; i < SCAN_BLOCKS; ++i) {
            int v = psum[i];
            psum[i] = acc;
            acc += v;
        }
    }
}

__global__ __launch_bounds__(512) void scan3_kernel(const int* __restrict__ rowcnt,
                                                    int* __restrict__ rowptr,
                                                    const int* __restrict__ psum,
                                                    int* __restrict__ cursor) {
    int t = threadIdx.x;
    int g = blockIdx.x * 512 + t;
    int v = rowptr[g] - rowcnt[g] + psum[blockIdx.x];
    rowptr[g] = v;
    cursor[g] = v;
}

// ---------------- fill CSR: column indices + precomputed edge weights ----------------
__global__ __launch_bounds__(256) void fill_kernel(const int* __restrict__ src,
                                                   const int* __restrict__ dst,
                                                   const float* __restrict__ dinv,
                                                   int* __restrict__ cursor,
                                                   int* __restrict__ ecol,
                                                   float* __restrict__ ew) {
    int e = blockIdx.x * 256 + threadIdx.x;
    if (e < N_EDGES) {
        int s = src[e], d = dst[e];
        if (s != d) {
            int pos = atomicAdd(&cursor[s], 1);
            ecol[pos] = d;
            ew[pos] = dinv[s] * dinv[d];
        }
    }
}

// ---------------- GEMM1: H = X @ W1 + b1, output packed bf16 ----------------
__global__ __launch_bounds__(256) void gemm1_kernel(const float* __restrict__ X,
                                                    const float* __restrict__ W,
                                                    const float* __restrict__ bias,
                                                    uint* __restrict__ Hbf) {
    __shared__ float Ast[16][128];
    __shared__ float Bs[16][128];
    const int t = threadIdx.x;
    const int rowBase = blockIdx.x * 128;
    const int rg = t >> 4, cg = t & 15;
    const int lr = t >> 1, lcp = (t & 1) * 2;

    float acc[8][8];
#pragma unroll
    for (int i = 0; i < 8; ++i)
#pragma unroll
        for (int j = 0; j < 8; ++j) acc[i][j] = 0.f;

    for (int kc = 0; kc < 128; kc += 16) {
        const int arow = rowBase + lr;
#pragma unroll
        for (int i = 0; i < 2; ++i) {
            const int col4 = lcp + i;
            float4 v = make_float4(0.f, 0.f, 0.f, 0.f);
            if (arow < N_NODES)
                v = *(const float4*)&X[arow * 128 + kc + col4 * 4];
            Ast[col4 * 4 + 0][lr] = v.x;
            Ast[col4 * 4 + 1][lr] = v.y;
            Ast[col4 * 4 + 2][lr] = v.z;
            Ast[col4 * 4 + 3][lr] = v.w;
        }
        {
            const int kr = t >> 4, c4 = t & 15;
#pragma unroll
            for (int i = 0; i < 2; ++i) {
                const int cc = c4 + i * 16;
                *(float4*)&Bs[kr][cc * 4] = *(const float4*)&W[(kc + kr) * 128 + cc * 4];
            }
        }
        __syncthreads();
#pragma unroll
        for (int kk = 0; kk < 16; ++kk) {
            float4 a0 = *(const float4*)&Ast[kk][rg * 8];
            float4 a1 = *(const float4*)&Ast[kk][rg * 8 + 4];
            float4 b0 = *(const float4*)&Bs[kk][cg * 8];
            float4 b1 = *(const float4*)&Bs[kk][cg * 8 + 4];
            float a[8] = {a0.x, a0.y, a0.z, a0.w, a1.x, a1.y, a1.z, a1.w};
            float b[8] = {b0.x, b0.y, b0.z, b0.w, b1.x, b1.y, b1.z, b1.w};
#pragma unroll
            for (int i = 0; i < 8; ++i)
#pragma unroll
                for (int j = 0; j < 8; ++j) acc[i][j] += a[i] * b[j];
        }
        __syncthreads();
    }

    float4 bb0 = *(const float4*)&bias[cg * 8];
    float4 bb1 = *(const float4*)&bias[cg * 8 + 4];
#pragma unroll
    for (int i = 0; i < 8; ++i) {
        const int row = rowBase + rg * 8 + i;
        if (row < N_NODES) {
            uint4 p;
            p.x = pack_bf2(acc[i][0] + bb0.x, acc[i][1] + bb0.y);
            p.y = pack_bf2(acc[i][2] + bb0.z, acc[i][3] + bb0.w);
            p.z = pack_bf2(acc[i][4] + bb1.x, acc[i][5] + bb1.y);
            p.w = pack_bf2(acc[i][6] + bb1.z, acc[i][7] + bb1.w);
            *(uint4*)&Hbf[row * 64 + cg * 4] = p;
        }
    }
}

// ---------------- GEMM2: H2 = relu(bn(H1agg)) @ W2 + b2, output packed bf16 ------
__global__ __launch_bounds__(256) void gemm2_kernel(const float* __restrict__ Hin,
                                                    const float* __restrict__ W,
                                                    const float* __restrict__ bias,
                                                    const float* __restrict__ scale,
                                                    const float* __restrict__ shift,
                                                    uint* __restrict__ Hbf) {
    __shared__ float Ast[16][128];
    __shared__ float Bs[16][64];
    const int t = threadIdx.x;
    const int rowBase = blockIdx.x * 128;
    const int rg = t >> 4, cg = t & 15;
    const int lr = t >> 1, lcp = (t & 1) * 2;

    float acc[8][4];
#pragma unroll
    for (int i = 0; i < 8; ++i)
#pragma unroll
        for (int j = 0; j < 4; ++j) acc[i][j] = 0.f;

    for (int kc = 0; kc < 128; kc += 16) {
        const int arow = rowBase + lr;
#pragma unroll
        for (int i = 0; i < 2; ++i) {
            const int col4 = lcp + i;
            const int kg = kc + col4 * 4;
            float4 v = make_float4(0.f, 0.f, 0.f, 0.f);
            if (arow < N_NODES) {
                float4 h = *(const float4*)&Hin[arow * 128 + kg];
                float4 sc = *(const float4*)&scale[kg];
                float4 sh = *(const float4*)&shift[kg];
                v.x = fmaxf(0.f, h.x * sc.x + sh.x);
                v.y = fmaxf(0.f, h.y * sc.y + sh.y);
                v.z = fmaxf(0.f, h.z * sc.z + sh.z);
                v.w = fmaxf(0.f, h.w * sc.w + sh.w);
            }
            Ast[col4 * 4 + 0][lr] = v.x;
            Ast[col4 * 4 + 1][lr] = v.y;
            Ast[col4 * 4 + 2][lr] = v.z;
            Ast[col4 * 4 + 3][lr] = v.w;
        }
        *(float4*)&Bs[t >> 4][(t & 15) * 4] =
            *(const float4*)&W[(kc + (t >> 4)) * 64 + (t & 15) * 4];
        __syncthreads();
#pragma unroll
        for (int kk = 0; kk < 16; ++kk) {
            float4 a0 = *(const float4*)&Ast[kk][rg * 8];
            float4 a1 = *(const float4*)&Ast[kk][rg * 8 + 4];
            float4 b0 = *(const float4*)&Bs[kk][cg * 4];
            float a[8] = {a0.x, a0.y, a0.z, a0.w, a1.x, a1.y, a1.z, a1.w};
            float b[4] = {b0.x, b0.y, b0.z, b0.w};
#pragma unroll
            for (int i = 0; i < 8; ++i)
#pragma unroll
                for (int j = 0; j < 4; ++j) acc[i][j] += a[i] * b[j];
        }
        __syncthreads();
    }

    float4 bb = *(const float4*)&bias[cg * 4];
#pragma unroll
    for (int i = 0; i < 8; ++i) {
        const int row = rowBase + rg * 8 + i;
        if (row < N_NODES) {
            uint2 p;
            p.x = pack_bf2(acc[i][0] + bb.x, acc[i][1] + bb.y);
            p.y = pack_bf2(acc[i][2] + bb.z, acc[i][3] + bb.w);
            *(uint2*)&Hbf[row * 32 + cg * 2] = p;
        }
    }
}

// ---------------- CSR gather SpMM over bf16 H, fp32 accumulate ----------------
// out[i][c] = dinv[i]^2*H[i][c] + sum_e ew[e]*H[ecol[e]][c]
// C=128: 16 lanes/row x 8ch; C=64: 8 lanes/row x 8ch. 16B gathers, unroll 4.
template <int C>
__global__ __launch_bounds__(256) void spmm_bf16_kernel(const int* __restrict__ rowptr,
                                                        const int* __restrict__ ecol,
                                                        const float* __restrict__ ew,
                                                        const float* __restrict__ dinv,
                                                        const uint* __restrict__ H,
                                                        float* __restrict__ out) {
    constexpr int LPR = C / 8;        // lanes per row
    constexpr int RPB = 256 / LPR;    // rows per block
    constexpr int US  = C / 2;        // uint row stride
    const int t = threadIdx.x;
    const int lane = t % LPR;
    const int row = blockIdx.x * RPB + t / LPR;
    if (row >= N_NODES) return;
    const int cu = lane * 4;          // uint offset (8 channels)
    const float di = dinv[row];

    float acc[8];
    {
        uint4 hv = *(const uint4*)&H[row * US + cu];
        float w = di * di;
        acc[0] = w * bfl(hv.x); acc[1] = w * bfh(hv.x);
        acc[2] = w * bfl(hv.y); acc[3] = w * bfh(hv.y);
        acc[4] = w * bfl(hv.z); acc[5] = w * bfh(hv.z);
        acc[6] = w * bfl(hv.w); acc[7] = w * bfh(hv.w);
    }
    const int e0 = rowptr[row], e1 = rowptr[row + 1];
    int e = e0;
    for (; e + 4 <= e1; e += 4) {
        int d0 = ecol[e + 0], d1 = ecol[e + 1], d2 = ecol[e + 2], d3 = ecol[e + 3];
        float w0 = ew[e + 0], w1 = ew[e + 1], w2 = ew[e + 2], w3 = ew[e + 3];
        uint4 h0 = *(const uint4*)&H[d0 * US + cu];
        uint4 h1 = *(const uint4*)&H[d1 * US + cu];
        uint4 h2 = *(const uint4*)&H[d2 * US + cu];
        uint4 h3 = *(const uint4*)&H[d3 * US + cu];
        acc8(acc, h0, w0);
        acc8(acc, h1, w1);
        acc8(acc, h2, w2);
        acc8(acc, h3, w3);
    }
    for (; e < e1; ++e) {
        int d = ecol[e];
        float w = ew[e];
        uint4 h = *(const uint4*)&H[d * US + cu];
        acc8(acc, h, w);
    }
    float4 o0 = make_float4(acc[0], acc[1], acc[2], acc[3]);
    float4 o1 = make_float4(acc[4], acc[5], acc[6], acc[7]);
    *(float4*)&out[row * C + lane * 8] = o0;
    *(float4*)&out[row * C + lane * 8 + 4] = o1;
}

// ---------------- BN statistics ----------------
__global__ __launch_bounds__(256) void bn_stats_kernel(const float* __restrict__ H,
                                                       float* __restrict__ sum,
                                                       float* __restrict__ sumsq) {
    int c = threadIdx.x & 127;
    int half = threadIdx.x >> 7;
    float s = 0.f, q = 0.f;
    for (int r = blockIdx.x * 2 + half; r < N_NODES; r += 512) {
        float v = H[r * 128 + c];
        s += v;
        q += v * v;
    }
    __shared__ float ls[256], lq[256];
    ls[threadIdx.x] = s;
    lq[threadIdx.x] = q;
    __syncthreads();
    if (half == 0) {
        atomicAdd(&sum[c], ls[c] + ls[c + 128]);
        atomicAdd(&sumsq[c], lq[c] + lq[c + 128]);
    }
}

__global__ void bn_finalize_kernel(const float* __restrict__ sum,
                                   const float* __restrict__ sumsq,
                                   const float* __restrict__ gamma,
                                   const float* __restrict__ beta,
                                   float* __restrict__ scale,
                                   float* __restrict__ shift) {
    int c = threadIdx.x;
    if (c < 128) {
        float mean = sum[c] * (1.0f / N_NODES);
        float var = sumsq[c] * (1.0f / N_NODES) - mean * mean;
        float sc = gamma[c] * rsqrtf(var + BN_EPS);
        scale[c] = sc;
        shift[c] = beta[c] - mean * sc;
    }
}

extern "C" void kernel_launch(void* const* d_in, const int* in_sizes, int n_in,
                              void* d_out, int out_size, void* d_ws, size_t ws_size,
                              hipStream_t stream) {
    const float* x     = (const float*)d_in[0];
    const int*   ei    = (const int*)d_in[1];
    const float* W1    = (const float*)d_in[2];
    const float* b1    = (const float*)d_in[3];
    const float* gamma = (const float*)d_in[4];
    const float* beta  = (const float*)d_in[5];
    const float* W2    = (const float*)d_in[6];
    const float* b2    = (const float*)d_in[7];
    float* out = (float*)d_out;
    const int* src = ei;
    const int* dst = ei + N_EDGES;

    // workspace layout (4-byte units)
    float* ws     = (float*)d_ws;
    float* dinv   = ws;                          // NPAD
    float* stats  = ws + NPAD;                   // 512
    int*   degN   = (int*)(ws + NPAD + 512);     // NPAD
    int*   rowcnt = degN + NPAD;                 // NPAD
    int*   rowptr = rowcnt + NPAD;               // NPAD
    int*   cursor = rowptr + NPAD;               // NPAD
    int*   psum   = cursor + NPAD;               // 128
    int*   ecol   = psum + 128;                  // N_EDGES
    float* ew     = (float*)(ecol + N_EDGES);    // N_EDGES
    uint*  h1bf   = (uint*)(ew + N_EDGES);       // N*64 uints (bf16 x128)
    float* h1agg  = (float*)(h1bf + N_NODES * 64);  // N*128 fp32
    uint*  h2bf   = h1bf;                        // alias: h1bf dead after spmm1
    float* sum    = stats;
    float* sumsq  = stats + 128;
    float* scale  = stats + 256;
    float* shift  = stats + 384;

    hipMemsetAsync(stats, 0, 512 * sizeof(float), stream);
    hipMemsetAsync(degN, 0, 2 * NPAD * sizeof(int), stream);  // degN + rowcnt

    count_kernel<<<(N_EDGES + 255) / 256, 256, 0, stream>>>(src, dst, degN, rowcnt);
    dinv_kernel<<<(N_NODES + 255) / 256, 256, 0, stream>>>(degN, dinv);

    scan1_kernel<<<SCAN_BLOCKS, 512, 0, stream>>>(rowcnt, rowptr, psum);
    scan2_kernel<<<1, 64, 0, stream>>>(psum);
    scan3_kernel<<<SCAN_BLOCKS, 512, 0, stream>>>(rowcnt, rowptr, psum, cursor);
    fill_kernel<<<(N_EDGES + 255) / 256, 256, 0, stream>>>(src, dst, dinv, cursor, ecol, ew);

    gemm1_kernel<<<(N_NODES + 127) / 128, 256, 0, stream>>>(x, W1, b1, h1bf);

    spmm_bf16_kernel<128><<<(N_NODES + 15) / 16, 256, 0, stream>>>(rowptr, ecol, ew, dinv, h1bf, h1agg);

    bn_stats_kernel<<<256, 256, 0, stream>>>(h1agg, sum, sumsq);
    bn_finalize_kernel<<<1, 128, 0, stream>>>(sum, sumsq, gamma, beta, scale, shift);

    gemm2_kernel<<<(N_NODES + 127) / 128, 256, 0, stream>>>(h1agg, W2, b2, scale, shift, h2bf);

    spmm_bf16_kernel<64><<<(N_NODES + 31) / 32, 256, 0, stream>>>(rowptr, ecol, ew, dinv, h2bf, out);
}

// Round 4
// 334.760 us; speedup vs baseline: 2.2370x; 1.0598x over previous
//
#include <hip/hip_runtime.h>

#define N_NODES 50000
#define N_EDGES 800000
#define BN_EPS 1e-5f
#define NPAD 50176          // N_NODES padded to 98*512 (and 196*256)
#define SCAN_BLOCKS 98      // 98*512 = 50176
#define NCOPY 8             // XCD-private histogram copies

typedef unsigned int uint;

// ---- bf16 helpers (stored as packed pairs in uint) ----
__device__ __forceinline__ float bfl(uint u) { return __uint_as_float(u << 16); }
__device__ __forceinline__ float bfh(uint u) { return __uint_as_float(u & 0xffff0000u); }
__device__ __forceinline__ uint pack_bf2(float a, float b) {
    uint ua = __float_as_uint(a), ub = __float_as_uint(b);
    ua += 0x7fffu + ((ua >> 16) & 1u);   // RNE
    ub += 0x7fffu + ((ub >> 16) & 1u);
    return (ua >> 16) | (ub & 0xffff0000u);
}
__device__ __forceinline__ void acc8(float* a, uint4 h, float w) {
    a[0] += w * bfl(h.x); a[1] += w * bfh(h.x);
    a[2] += w * bfl(h.y); a[3] += w * bfh(h.y);
    a[4] += w * bfl(h.z); a[5] += w * bfh(h.z);
    a[6] += w * bfl(h.w); a[7] += w * bfh(h.w);
}

// ---------------- edge counting into XCD-private copies ----------------
__global__ __launch_bounds__(256) void count_kernel(const int* __restrict__ src,
                                                    const int* __restrict__ dst,
                                                    int* __restrict__ degN8,
                                                    int* __restrict__ cnt8) {
    int e = blockIdx.x * 256 + threadIdx.x;
    int k = blockIdx.x & (NCOPY - 1);
    if (e < N_EDGES) {
        int s = src[e], d = dst[e];
        if (s != d) {
            atomicAdd(&degN8[k * NPAD + d], 1);
            atomicAdd(&cnt8[k * NPAD + s], 1);
        }
    }
}

// ---------------- reduce copies: dinv + total rowcnt ----------------
__global__ __launch_bounds__(256) void dinv_rowcnt_kernel(const int* __restrict__ degN8,
                                                          const int* __restrict__ cnt8,
                                                          float* __restrict__ dinv,
                                                          int* __restrict__ rowcnt) {
    int i = blockIdx.x * 256 + threadIdx.x;   // i < NPAD
    int dg = 0, rc = 0;
#pragma unroll
    for (int k = 0; k < NCOPY; ++k) {
        dg += degN8[k * NPAD + i];
        rc += cnt8[k * NPAD + i];
    }
    rowcnt[i] = rc;
    if (i < N_NODES) dinv[i] = rsqrtf((float)dg + 1.0f);
}

// ---------------- exclusive scan of rowcnt -> rowptr ----------------
__global__ __launch_bounds__(512) void scan1_kernel(const int* __restrict__ rowcnt,
                                                    int* __restrict__ rowptr,
                                                    int* __restrict__ psum) {
    __shared__ int buf[512];
    int t = threadIdx.x;
    int g = blockIdx.x * 512 + t;
    buf[t] = rowcnt[g];
    __syncthreads();
#pragma unroll
    for (int off = 1; off < 512; off <<= 1) {
        int x = (t >= off) ? buf[t - off] : 0;
        __syncthreads();
        buf[t] += x;
        __syncthreads();
    }
    rowptr[g] = buf[t];
    if (t == 511) psum[blockIdx.x] = buf[511];
}

__global__ void scan2_kernel(int* __restrict__ psum) {
    if (threadIdx.x == 0) {
        int acc = 0;
        for (int i = 0; i < SCAN_BLOCKS; ++i) {
            int v = psum[i];
            psum[i] = acc;
            acc += v;
        }
    }
}

__global__ __launch_bounds__(512) void scan3_kernel(const int* __restrict__ rowcnt,
                                                    int* __restrict__ rowptr,
                                                    const int* __restrict__ psum) {
    int t = threadIdx.x;
    int g = blockIdx.x * 512 + t;
    rowptr[g] = rowptr[g] - rowcnt[g] + psum[blockIdx.x];
}

// ---------------- per-(row,copy) cursor bases ----------------
// cursor[k][r] = rowptr[r] + sum_{k'<k} cnt8[k'][r]  -> row's edges stay contiguous
__global__ __launch_bounds__(256) void cursor_init_kernel(const int* __restrict__ rowptr,
                                                          const int* __restrict__ cnt8,
                                                          int* __restrict__ cursor) {
    int r = blockIdx.x * 256 + threadIdx.x;   // r < NPAD
    int s = rowptr[r];
#pragma unroll
    for (int k = 0; k < NCOPY; ++k) {
        cursor[k * NPAD + r] = s;
        s += cnt8[k * NPAD + r];
    }
}

// ---------------- fill CSR: fused (col, weight) pairs ----------------
__global__ __launch_bounds__(256) void fill_kernel(const int* __restrict__ src,
                                                   const int* __restrict__ dst,
                                                   const float* __restrict__ dinv,
                                                   int* __restrict__ cursor,
                                                   int2* __restrict__ epair) {
    int e = blockIdx.x * 256 + threadIdx.x;
    int k = blockIdx.x & (NCOPY - 1);
    if (e < N_EDGES) {
        int s = src[e], d = dst[e];
        if (s != d) {
            int pos = atomicAdd(&cursor[k * NPAD + s], 1);
            epair[pos] = make_int2(d, __float_as_int(dinv[s] * dinv[d]));
        }
    }
}

// ---------------- GEMM1: H = X @ W1 + b1, output packed bf16 ----------------
__global__ __launch_bounds__(256) void gemm1_kernel(const float* __restrict__ X,
                                                    const float* __restrict__ W,
                                                    const float* __restrict__ bias,
                                                    uint* __restrict__ Hbf) {
    __shared__ float Ast[16][128];
    __shared__ float Bs[16][128];
    const int t = threadIdx.x;
    const int rowBase = blockIdx.x * 128;
    const int rg = t >> 4, cg = t & 15;
    const int lr = t >> 1, lcp = (t & 1) * 2;

    float acc[8][8];
#pragma unroll
    for (int i = 0; i < 8; ++i)
#pragma unroll
        for (int j = 0; j < 8; ++j) acc[i][j] = 0.f;

    for (int kc = 0; kc < 128; kc += 16) {
        const int arow = rowBase + lr;
#pragma unroll
        for (int i = 0; i < 2; ++i) {
            const int col4 = lcp + i;
            float4 v = make_float4(0.f, 0.f, 0.f, 0.f);
            if (arow < N_NODES)
                v = *(const float4*)&X[arow * 128 + kc + col4 * 4];
            Ast[col4 * 4 + 0][lr] = v.x;
            Ast[col4 * 4 + 1][lr] = v.y;
            Ast[col4 * 4 + 2][lr] = v.z;
            Ast[col4 * 4 + 3][lr] = v.w;
        }
        {
            const int kr = t >> 4, c4 = t & 15;
#pragma unroll
            for (int i = 0; i < 2; ++i) {
                const int cc = c4 + i * 16;
                *(float4*)&Bs[kr][cc * 4] = *(const float4*)&W[(kc + kr) * 128 + cc * 4];
            }
        }
        __syncthreads();
#pragma unroll
        for (int kk = 0; kk < 16; ++kk) {
            float4 a0 = *(const float4*)&Ast[kk][rg * 8];
            float4 a1 = *(const float4*)&Ast[kk][rg * 8 + 4];
            float4 b0 = *(const float4*)&Bs[kk][cg * 8];
            float4 b1 = *(const float4*)&Bs[kk][cg * 8 + 4];
            float a[8] = {a0.x, a0.y, a0.z, a0.w, a1.x, a1.y, a1.z, a1.w};
            float b[8] = {b0.x, b0.y, b0.z, b0.w, b1.x, b1.y, b1.z, b1.w};
#pragma unroll
            for (int i = 0; i < 8; ++i)
#pragma unroll
                for (int j = 0; j < 8; ++j) acc[i][j] += a[i] * b[j];
        }
        __syncthreads();
    }

    float4 bb0 = *(const float4*)&bias[cg * 8];
    float4 bb1 = *(const float4*)&bias[cg * 8 + 4];
#pragma unroll
    for (int i = 0; i < 8; ++i) {
        const int row = rowBase + rg * 8 + i;
        if (row < N_NODES) {
            uint4 p;
            p.x = pack_bf2(acc[i][0] + bb0.x, acc[i][1] + bb0.y);
            p.y = pack_bf2(acc[i][2] + bb0.z, acc[i][3] + bb0.w);
            p.z = pack_bf2(acc[i][4] + bb1.x, acc[i][5] + bb1.y);
            p.w = pack_bf2(acc[i][6] + bb1.z, acc[i][7] + bb1.w);
            *(uint4*)&Hbf[row * 64 + cg * 4] = p;
        }
    }
}

// ---------------- GEMM2: H2 = relu(bn(H1agg)) @ W2 + b2, output packed bf16 ------
__global__ __launch_bounds__(256) void gemm2_kernel(const float* __restrict__ Hin,
                                                    const float* __restrict__ W,
                                                    const float* __restrict__ bias,
                                                    const float* __restrict__ scale,
                                                    const float* __restrict__ shift,
                                                    uint* __restrict__ Hbf) {
    __shared__ float Ast[16][128];
    __shared__ float Bs[16][64];
    const int t = threadIdx.x;
    const int rowBase = blockIdx.x * 128;
    const int rg = t >> 4, cg = t & 15;
    const int lr = t >> 1, lcp = (t & 1) * 2;

    float acc[8][4];
#pragma unroll
    for (int i = 0; i < 8; ++i)
#pragma unroll
        for (int j = 0; j < 4; ++j) acc[i][j] = 0.f;

    for (int kc = 0; kc < 128; kc += 16) {
        const int arow = rowBase + lr;
#pragma unroll
        for (int i = 0; i < 2; ++i) {
            const int col4 = lcp + i;
            const int kg = kc + col4 * 4;
            float4 v = make_float4(0.f, 0.f, 0.f, 0.f);
            if (arow < N_NODES) {
                float4 h = *(const float4*)&Hin[arow * 128 + kg];
                float4 sc = *(const float4*)&scale[kg];
                float4 sh = *(const float4*)&shift[kg];
                v.x = fmaxf(0.f, h.x * sc.x + sh.x);
                v.y = fmaxf(0.f, h.y * sc.y + sh.y);
                v.z = fmaxf(0.f, h.z * sc.z + sh.z);
                v.w = fmaxf(0.f, h.w * sc.w + sh.w);
            }
            Ast[col4 * 4 + 0][lr] = v.x;
            Ast[col4 * 4 + 1][lr] = v.y;
            Ast[col4 * 4 + 2][lr] = v.z;
            Ast[col4 * 4 + 3][lr] = v.w;
        }
        *(float4*)&Bs[t >> 4][(t & 15) * 4] =
            *(const float4*)&W[(kc + (t >> 4)) * 64 + (t & 15) * 4];
        __syncthreads();
#pragma unroll
        for (int kk = 0; kk < 16; ++kk) {
            float4 a0 = *(const float4*)&Ast[kk][rg * 8];
            float4 a1 = *(const float4*)&Ast[kk][rg * 8 + 4];
            float4 b0 = *(const float4*)&Bs[kk][cg * 4];
            float a[8] = {a0.x, a0.y, a0.z, a0.w, a1.x, a1.y, a1.z, a1.w};
            float b[4] = {b0.x, b0.y, b0.z, b0.w};
#pragma unroll
            for (int i = 0; i < 8; ++i)
#pragma unroll
                for (int j = 0; j < 4; ++j) acc[i][j] += a[i] * b[j];
        }
        __syncthreads();
    }

    float4 bb = *(const float4*)&bias[cg * 4];
#pragma unroll
    for (int i = 0; i < 8; ++i) {
        const int row = rowBase + rg * 8 + i;
        if (row < N_NODES) {
            uint2 p;
            p.x = pack_bf2(acc[i][0] + bb.x, acc[i][1] + bb.y);
            p.y = pack_bf2(acc[i][2] + bb.z, acc[i][3] + bb.w);
            *(uint2*)&Hbf[row * 32 + cg * 2] = p;
        }
    }
}

// ---------------- CSR gather SpMM over bf16 H, fp32 accumulate ----------------
template <int C>
__global__ __launch_bounds__(256) void spmm_bf16_kernel(const int* __restrict__ rowptr,
                                                        const int2* __restrict__ epair,
                                                        const float* __restrict__ dinv,
                                                        const uint* __restrict__ H,
                                                        float* __restrict__ out) {
    constexpr int LPR = C / 8;        // lanes per row
    constexpr int RPB = 256 / LPR;    // rows per block
    constexpr int US  = C / 2;        // uint row stride
    const int t = threadIdx.x;
    const int lane = t % LPR;
    const int row = blockIdx.x * RPB + t / LPR;
    if (row >= N_NODES) return;
    const int cu = lane * 4;          // uint offset (8 channels)
    const float di = dinv[row];

    float acc[8];
    {
        uint4 hv = *(const uint4*)&H[row * US + cu];
        float w = di * di;
        acc[0] = w * bfl(hv.x); acc[1] = w * bfh(hv.x);
        acc[2] = w * bfl(hv.y); acc[3] = w * bfh(hv.y);
        acc[4] = w * bfl(hv.z); acc[5] = w * bfh(hv.z);
        acc[6] = w * bfl(hv.w); acc[7] = w * bfh(hv.w);
    }
    const int e0 = rowptr[row], e1 = rowptr[row + 1];
    int e = e0;
    for (; e + 4 <= e1; e += 4) {
        int2 p0 = epair[e + 0], p1 = epair[e + 1], p2 = epair[e + 2], p3 = epair[e + 3];
        uint4 h0 = *(const uint4*)&H[p0.x * US + cu];
        uint4 h1 = *(const uint4*)&H[p1.x * US + cu];
        uint4 h2 = *(const uint4*)&H[p2.x * US + cu];
        uint4 h3 = *(const uint4*)&H[p3.x * US + cu];
        acc8(acc, h0, __int_as_float(p0.y));
        acc8(acc, h1, __int_as_float(p1.y));
        acc8(acc, h2, __int_as_float(p2.y));
        acc8(acc, h3, __int_as_float(p3.y));
    }
    for (; e < e1; ++e) {
        int2 p = epair[e];
        uint4 h = *(const uint4*)&H[p.x * US + cu];
        acc8(acc, h, __int_as_float(p.y));
    }
    float4 o0 = make_float4(acc[0], acc[1], acc[2], acc[3]);
    float4 o1 = make_float4(acc[4], acc[5], acc[6], acc[7]);
    *(float4*)&out[row * C + lane * 8] = o0;
    *(float4*)&out[row * C + lane * 8 + 4] = o1;
}

// ---------------- BN statistics ----------------
__global__ __launch_bounds__(256) void bn_stats_kernel(const float* __restrict__ H,
                                                       float* __restrict__ sum,
                                                       float* __restrict__ sumsq) {
    int c = threadIdx.x & 127;
    int half = threadIdx.x >> 7;
    float s = 0.f, q = 0.f;
    for (int r = blockIdx.x * 2 + half; r < N_NODES; r += 512) {
        float v = H[r * 128 + c];
        s += v;
        q += v * v;
    }
    __shared__ float ls[256], lq[256];
    ls[threadIdx.x] = s;
    lq[threadIdx.x] = q;
    __syncthreads();
    if (half == 0) {
        atomicAdd(&sum[c], ls[c] + ls[c + 128]);
        atomicAdd(&sumsq[c], lq[c] + lq[c + 128]);
    }
}

__global__ void bn_finalize_kernel(const float* __restrict__ sum,
                                   const float* __restrict__ sumsq,
                                   const float* __restrict__ gamma,
                                   const float* __restrict__ beta,
                                   float* __restrict__ scale,
                                   float* __restrict__ shift) {
    int c = threadIdx.x;
    if (c < 128) {
        float mean = sum[c] * (1.0f / N_NODES);
        float var = sumsq[c] * (1.0f / N_NODES) - mean * mean;
        float sc = gamma[c] * rsqrtf(var + BN_EPS);
        scale[c] = sc;
        shift[c] = beta[c] - mean * sc;
    }
}

extern "C" void kernel_launch(void* const* d_in, const int* in_sizes, int n_in,
                              void* d_out, int out_size, void* d_ws, size_t ws_size,
                              hipStream_t stream) {
    const float* x     = (const float*)d_in[0];
    const int*   ei    = (const int*)d_in[1];
    const float* W1    = (const float*)d_in[2];
    const float* b1    = (const float*)d_in[3];
    const float* gamma = (const float*)d_in[4];
    const float* beta  = (const float*)d_in[5];
    const float* W2    = (const float*)d_in[6];
    const float* b2    = (const float*)d_in[7];
    float* out = (float*)d_out;
    const int* src = ei;
    const int* dst = ei + N_EDGES;

    // workspace layout (4-byte units)
    float* ws     = (float*)d_ws;
    float* dinv   = ws;                             // NPAD
    float* stats  = ws + NPAD;                      // 512
    int*   degN8  = (int*)(ws + NPAD + 512);        // 8*NPAD
    int*   cnt8   = degN8 + NCOPY * NPAD;           // 8*NPAD
    int*   rowcnt = cnt8 + NCOPY * NPAD;            // NPAD
    int*   rowptr = rowcnt + NPAD;                  // NPAD
    int*   cursor = rowptr + NPAD;                  // 8*NPAD
    int*   psum   = cursor + NCOPY * NPAD;          // 128
    int2*  epair  = (int2*)(psum + 128);            // N_EDGES (8B aligned)
    uint*  h1bf   = (uint*)(epair + N_EDGES);       // N*64 uints (bf16 x128)
    float* h1agg  = (float*)(h1bf + N_NODES * 64);  // N*128 fp32
    uint*  h2bf   = h1bf;                           // alias (h1bf dead after spmm1)
    float* sum    = stats;
    float* sumsq  = stats + 128;
    float* scale  = stats + 256;
    float* shift  = stats + 384;

    hipMemsetAsync(stats, 0, 512 * sizeof(float), stream);
    hipMemsetAsync(degN8, 0, 2 * NCOPY * NPAD * sizeof(int), stream);  // degN8 + cnt8

    count_kernel<<<(N_EDGES + 255) / 256, 256, 0, stream>>>(src, dst, degN8, cnt8);
    dinv_rowcnt_kernel<<<NPAD / 256, 256, 0, stream>>>(degN8, cnt8, dinv, rowcnt);

    scan1_kernel<<<SCAN_BLOCKS, 512, 0, stream>>>(rowcnt, rowptr, psum);
    scan2_kernel<<<1, 64, 0, stream>>>(psum);
    scan3_kernel<<<SCAN_BLOCKS, 512, 0, stream>>>(rowcnt, rowptr, psum);
    cursor_init_kernel<<<NPAD / 256, 256, 0, stream>>>(rowptr, cnt8, cursor);
    fill_kernel<<<(N_EDGES + 255) / 256, 256, 0, stream>>>(src, dst, dinv, cursor, epair);

    gemm1_kernel<<<(N_NODES + 127) / 128, 256, 0, stream>>>(x, W1, b1, h1bf);

    spmm_bf16_kernel<128><<<(N_NODES + 15) / 16, 256, 0, stream>>>(rowptr, epair, dinv, h1bf, h1agg);

    bn_stats_kernel<<<256, 256, 0, stream>>>(h1agg, sum, sumsq);
    bn_finalize_kernel<<<1, 128, 0, stream>>>(sum, sumsq, gamma, beta, scale, shift);

    gemm2_kernel<<<(N_NODES + 127) / 128, 256, 0, stream>>>(h1agg, W2, b2, scale, shift, h2bf);

    spmm_bf16_kernel<64><<<(N_NODES + 31) / 32, 256, 0, stream>>>(rowptr, epair, dinv, h2bf, out);
}

// Round 5
// 295.613 us; speedup vs baseline: 2.5333x; 1.1324x over previous
//
#include <hip/hip_runtime.h>

#define N_NODES 50000
#define N_EDGES 800000
#define BN_EPS 1e-5f
#define NPAD 50176          // N_NODES padded to 98*512
#define SCAN_BLOCKS 98      // 98*512 = 50176

// CSR-build tiling: 64 edge slices x 7 node ranges of 8192 bins
#define S_SLICES 64
#define R_RANGES 7
#define BINS 8192
#define NP7 (R_RANGES * BINS)        // 57344 bins per slice (covers NPAD)
#define ES (N_EDGES / S_SLICES)      // 12500 edges per slice

typedef unsigned int uint;
typedef unsigned short ushort;

// ---- bf16 helpers (stored as packed pairs in uint) ----
__device__ __forceinline__ float bfl(uint u) { return __uint_as_float(u << 16); }
__device__ __forceinline__ float bfh(uint u) { return __uint_as_float(u & 0xffff0000u); }
__device__ __forceinline__ uint pack_bf2(float a, float b) {
    uint ua = __float_as_uint(a), ub = __float_as_uint(b);
    ua += 0x7fffu + ((ua >> 16) & 1u);   // RNE
    ub += 0x7fffu + ((ub >> 16) & 1u);
    return (ua >> 16) | (ub & 0xffff0000u);
}
__device__ __forceinline__ void acc8(float* a, uint4 h, float w) {
    a[0] += w * bfl(h.x); a[1] += w * bfh(h.x);
    a[2] += w * bfl(h.y); a[3] += w * bfh(h.y);
    a[4] += w * bfl(h.z); a[5] += w * bfh(h.z);
    a[6] += w * bfl(h.w); a[7] += w * bfh(h.w);
}

// ---------------- count: LDS histograms per (slice, range), plain-store partials ----
__global__ __launch_bounds__(256) void count_hist_kernel(const int* __restrict__ src,
                                                         const int* __restrict__ dst,
                                                         ushort* __restrict__ part_cnt,
                                                         ushort* __restrict__ part_deg) {
    __shared__ uint cnt_lds[BINS];
    __shared__ uint deg_lds[BINS];
    const int s = blockIdx.x / R_RANGES;
    const int r = blockIdx.x % R_RANGES;
    const int base = r * BINS;
    for (int j = threadIdx.x; j < BINS; j += 256) { cnt_lds[j] = 0u; deg_lds[j] = 0u; }
    __syncthreads();
    const int e0 = s * ES;
    for (int i = threadIdx.x; i < ES; i += 256) {
        int e = e0 + i;
        int ss = src[e], dd = dst[e];
        if (ss != dd) {
            int a = ss - base;
            if ((unsigned)a < (unsigned)BINS) atomicAdd(&cnt_lds[a], 1u);
            int b = dd - base;
            if ((unsigned)b < (unsigned)BINS) atomicAdd(&deg_lds[b], 1u);
        }
    }
    __syncthreads();
    uint* pc = (uint*)&part_cnt[s * NP7 + base];
    uint* pd = (uint*)&part_deg[s * NP7 + base];
    for (int j = threadIdx.x; j < BINS / 2; j += 256) {
        pc[j] = (cnt_lds[2 * j] & 0xffffu) | (cnt_lds[2 * j + 1] << 16);
        pd[j] = (deg_lds[2 * j] & 0xffffu) | (deg_lds[2 * j + 1] << 16);
    }
}

// ---------------- reduce partials: dinv + total rowcnt (2 nodes/thread) ----------------
__global__ __launch_bounds__(256) void dinv_rowcnt_kernel(const ushort* __restrict__ part_deg,
                                                          const ushort* __restrict__ part_cnt,
                                                          float* __restrict__ dinv,
                                                          int* __restrict__ rowcnt) {
    int i = (blockIdx.x * 256 + threadIdx.x) * 2;   // i < NPAD, even
    uint dg0 = 0, dg1 = 0, rc0 = 0, rc1 = 0;
#pragma unroll 8
    for (int s = 0; s < S_SLICES; ++s) {
        uint vd = *(const uint*)&part_deg[s * NP7 + i];
        uint vc = *(const uint*)&part_cnt[s * NP7 + i];
        dg0 += vd & 0xffffu; dg1 += vd >> 16;
        rc0 += vc & 0xffffu; rc1 += vc >> 16;
    }
    *(int2*)&rowcnt[i] = make_int2((int)rc0, (int)rc1);
    if (i < N_NODES) dinv[i] = rsqrtf((float)dg0 + 1.0f);
    if (i + 1 < N_NODES) dinv[i + 1] = rsqrtf((float)dg1 + 1.0f);
}

// ---------------- exclusive scan of rowcnt -> rowptr ----------------
__global__ __launch_bounds__(512) void scan1_kernel(const int* __restrict__ rowcnt,
                                                    int* __restrict__ rowptr,
                                                    int* __restrict__ psum) {
    __shared__ int buf[512];
    int t = threadIdx.x;
    int g = blockIdx.x * 512 + t;
    buf[t] = rowcnt[g];
    __syncthreads();
#pragma unroll
    for (int off = 1; off < 512; off <<= 1) {
        int x = (t >= off) ? buf[t - off] : 0;
        __syncthreads();
        buf[t] += x;
        __syncthreads();
    }
    rowptr[g] = buf[t];
    if (t == 511) psum[blockIdx.x] = buf[511];
}

__global__ void scan2_kernel(int* __restrict__ psum) {
    if (threadIdx.x == 0) {
        int acc = 0;
        for (int i = 0; i < SCAN_BLOCKS; ++i) {
            int v = psum[i];
            psum[i] = acc;
            acc += v;
        }
    }
}

__global__ __launch_bounds__(512) void scan3_kernel(const int* __restrict__ rowcnt,
                                                    int* __restrict__ rowptr,
                                                    const int* __restrict__ psum) {
    int t = threadIdx.x;
    int g = blockIdx.x * 512 + t;
    rowptr[g] = rowptr[g] - rowcnt[g] + psum[blockIdx.x];
}

// ---------------- per-(slice,node) cursor bases (2 nodes/thread) ----------------
__global__ __launch_bounds__(256) void cursor_init_kernel(const int* __restrict__ rowptr,
                                                          const ushort* __restrict__ part_cnt,
                                                          int* __restrict__ cursor) {
    int i = (blockIdx.x * 256 + threadIdx.x) * 2;   // i < NPAD, even
    int b0 = rowptr[i], b1 = rowptr[i + 1];
#pragma unroll 8
    for (int s = 0; s < S_SLICES; ++s) {
        *(int2*)&cursor[s * NP7 + i] = make_int2(b0, b1);
        uint vc = *(const uint*)&part_cnt[s * NP7 + i];
        b0 += (int)(vc & 0xffffu);
        b1 += (int)(vc >> 16);
    }
}

// ---------------- fill CSR via LDS cursors: (col, weight) pairs ----------------
__global__ __launch_bounds__(256) void fill_lds_kernel(const int* __restrict__ src,
                                                       const int* __restrict__ dst,
                                                       const float* __restrict__ dinv,
                                                       const int* __restrict__ cursor,
                                                       int2* __restrict__ epair) {
    __shared__ int curs[BINS];
    const int s = blockIdx.x / R_RANGES;
    const int r = blockIdx.x % R_RANGES;
    const int base = r * BINS;
    const int* gc = &cursor[s * NP7 + base];
    for (int j = threadIdx.x; j < BINS; j += 256) curs[j] = gc[j];
    __syncthreads();
    const int e0 = s * ES;
    for (int i = threadIdx.x; i < ES; i += 256) {
        int e = e0 + i;
        int ss = src[e], dd = dst[e];
        int a = ss - base;
        if (ss != dd && (unsigned)a < (unsigned)BINS) {
            int pos = atomicAdd(&curs[a], 1);
            epair[pos] = make_int2(dd, __float_as_int(dinv[ss] * dinv[dd]));
        }
    }
}

// ---------------- GEMM1: H = X @ W1 + b1, output packed bf16 ----------------
__global__ __launch_bounds__(256) void gemm1_kernel(const float* __restrict__ X,
                                                    const float* __restrict__ W,
                                                    const float* __restrict__ bias,
                                                    uint* __restrict__ Hbf) {
    __shared__ float Ast[16][128];
    __shared__ float Bs[16][128];
    const int t = threadIdx.x;
    const int rowBase = blockIdx.x * 128;
    const int rg = t >> 4, cg = t & 15;
    const int lr = t >> 1, lcp = (t & 1) * 2;

    float acc[8][8];
#pragma unroll
    for (int i = 0; i < 8; ++i)
#pragma unroll
        for (int j = 0; j < 8; ++j) acc[i][j] = 0.f;

    for (int kc = 0; kc < 128; kc += 16) {
        const int arow = rowBase + lr;
#pragma unroll
        for (int i = 0; i < 2; ++i) {
            const int col4 = lcp + i;
            float4 v = make_float4(0.f, 0.f, 0.f, 0.f);
            if (arow < N_NODES)
                v = *(const float4*)&X[arow * 128 + kc + col4 * 4];
            Ast[col4 * 4 + 0][lr] = v.x;
            Ast[col4 * 4 + 1][lr] = v.y;
            Ast[col4 * 4 + 2][lr] = v.z;
            Ast[col4 * 4 + 3][lr] = v.w;
        }
        {
            const int kr = t >> 4, c4 = t & 15;
#pragma unroll
            for (int i = 0; i < 2; ++i) {
                const int cc = c4 + i * 16;
                *(float4*)&Bs[kr][cc * 4] = *(const float4*)&W[(kc + kr) * 128 + cc * 4];
            }
        }
        __syncthreads();
#pragma unroll
        for (int kk = 0; kk < 16; ++kk) {
            float4 a0 = *(const float4*)&Ast[kk][rg * 8];
            float4 a1 = *(const float4*)&Ast[kk][rg * 8 + 4];
            float4 b0 = *(const float4*)&Bs[kk][cg * 8];
            float4 b1 = *(const float4*)&Bs[kk][cg * 8 + 4];
            float a[8] = {a0.x, a0.y, a0.z, a0.w, a1.x, a1.y, a1.z, a1.w};
            float b[8] = {b0.x, b0.y, b0.z, b0.w, b1.x, b1.y, b1.z, b1.w};
#pragma unroll
            for (int i = 0; i < 8; ++i)
#pragma unroll
                for (int j = 0; j < 8; ++j) acc[i][j] += a[i] * b[j];
        }
        __syncthreads();
    }

    float4 bb0 = *(const float4*)&bias[cg * 8];
    float4 bb1 = *(const float4*)&bias[cg * 8 + 4];
#pragma unroll
    for (int i = 0; i < 8; ++i) {
        const int row = rowBase + rg * 8 + i;
        if (row < N_NODES) {
            uint4 p;
            p.x = pack_bf2(acc[i][0] + bb0.x, acc[i][1] + bb0.y);
            p.y = pack_bf2(acc[i][2] + bb0.z, acc[i][3] + bb0.w);
            p.z = pack_bf2(acc[i][4] + bb1.x, acc[i][5] + bb1.y);
            p.w = pack_bf2(acc[i][6] + bb1.z, acc[i][7] + bb1.w);
            *(uint4*)&Hbf[row * 64 + cg * 4] = p;
        }
    }
}

// ---------------- GEMM2: H2 = relu(bn(H1agg)) @ W2 + b2, output packed bf16 ------
__global__ __launch_bounds__(256) void gemm2_kernel(const float* __restrict__ Hin,
                                                    const float* __restrict__ W,
                                                    const float* __restrict__ bias,
                                                    const float* __restrict__ scale,
                                                    const float* __restrict__ shift,
                                                    uint* __restrict__ Hbf) {
    __shared__ float Ast[16][128];
    __shared__ float Bs[16][64];
    const int t = threadIdx.x;
    const int rowBase = blockIdx.x * 128;
    const int rg = t >> 4, cg = t & 15;
    const int lr = t >> 1, lcp = (t & 1) * 2;

    float acc[8][4];
#pragma unroll
    for (int i = 0; i < 8; ++i)
#pragma unroll
        for (int j = 0; j < 4; ++j) acc[i][j] = 0.f;

    for (int kc = 0; kc < 128; kc += 16) {
        const int arow = rowBase + lr;
#pragma unroll
        for (int i = 0; i < 2; ++i) {
            const int col4 = lcp + i;
            const int kg = kc + col4 * 4;
            float4 v = make_float4(0.f, 0.f, 0.f, 0.f);
            if (arow < N_NODES) {
                float4 h = *(const float4*)&Hin[arow * 128 + kg];
                float4 sc = *(const float4*)&scale[kg];
                float4 sh = *(const float4*)&shift[kg];
                v.x = fmaxf(0.f, h.x * sc.x + sh.x);
                v.y = fmaxf(0.f, h.y * sc.y + sh.y);
                v.z = fmaxf(0.f, h.z * sc.z + sh.z);
                v.w = fmaxf(0.f, h.w * sc.w + sh.w);
            }
            Ast[col4 * 4 + 0][lr] = v.x;
            Ast[col4 * 4 + 1][lr] = v.y;
            Ast[col4 * 4 + 2][lr] = v.z;
            Ast[col4 * 4 + 3][lr] = v.w;
        }
        *(float4*)&Bs[t >> 4][(t & 15) * 4] =
            *(const float4*)&W[(kc + (t >> 4)) * 64 + (t & 15) * 4];
        __syncthreads();
#pragma unroll
        for (int kk = 0; kk < 16; ++kk) {
            float4 a0 = *(const float4*)&Ast[kk][rg * 8];
            float4 a1 = *(const float4*)&Ast[kk][rg * 8 + 4];
            float4 b0 = *(const float4*)&Bs[kk][cg * 4];
            float a[8] = {a0.x, a0.y, a0.z, a0.w, a1.x, a1.y, a1.z, a1.w};
            float b[4] = {b0.x, b0.y, b0.z, b0.w};
#pragma unroll
            for (int i = 0; i < 8; ++i)
#pragma unroll
                for (int j = 0; j < 4; ++j) acc[i][j] += a[i] * b[j];
        }
        __syncthreads();
    }

    float4 bb = *(const float4*)&bias[cg * 4];
#pragma unroll
    for (int i = 0; i < 8; ++i) {
        const int row = rowBase + rg * 8 + i;
        if (row < N_NODES) {
            uint2 p;
            p.x = pack_bf2(acc[i][0] + bb.x, acc[i][1] + bb.y);
            p.y = pack_bf2(acc[i][2] + bb.z, acc[i][3] + bb.w);
            *(uint2*)&Hbf[row * 32 + cg * 2] = p;
        }
    }
}

// ---------------- CSR gather SpMM over bf16 H, fp32 accumulate ----------------
template <int C>
__global__ __launch_bounds__(256) void spmm_bf16_kernel(const int* __restrict__ rowptr,
                                                        const int2* __restrict__ epair,
                                                        const float* __restrict__ dinv,
                                                        const uint* __restrict__ H,
                                                        float* __restrict__ out) {
    constexpr int LPR = C / 8;        // lanes per row
    constexpr int RPB = 256 / LPR;    // rows per block
    constexpr int US  = C / 2;        // uint row stride
    const int t = threadIdx.x;
    const int lane = t % LPR;
    const int row = blockIdx.x * RPB + t / LPR;
    if (row >= N_NODES) return;
    const int cu = lane * 4;          // uint offset (8 channels)
    const float di = dinv[row];

    float acc[8];
    {
        uint4 hv = *(const uint4*)&H[row * US + cu];
        float w = di * di;
        acc[0] = w * bfl(hv.x); acc[1] = w * bfh(hv.x);
        acc[2] = w * bfl(hv.y); acc[3] = w * bfh(hv.y);
        acc[4] = w * bfl(hv.z); acc[5] = w * bfh(hv.z);
        acc[6] = w * bfl(hv.w); acc[7] = w * bfh(hv.w);
    }
    const int e0 = rowptr[row], e1 = rowptr[row + 1];
    int e = e0;
    for (; e + 4 <= e1; e += 4) {
        int2 p0 = epair[e + 0], p1 = epair[e + 1], p2 = epair[e + 2], p3 = epair[e + 3];
        uint4 h0 = *(const uint4*)&H[p0.x * US + cu];
        uint4 h1 = *(const uint4*)&H[p1.x * US + cu];
        uint4 h2 = *(const uint4*)&H[p2.x * US + cu];
        uint4 h3 = *(const uint4*)&H[p3.x * US + cu];
        acc8(acc, h0, __int_as_float(p0.y));
        acc8(acc, h1, __int_as_float(p1.y));
        acc8(acc, h2, __int_as_float(p2.y));
        acc8(acc, h3, __int_as_float(p3.y));
    }
    for (; e < e1; ++e) {
        int2 p = epair[e];
        uint4 h = *(const uint4*)&H[p.x * US + cu];
        acc8(acc, h, __int_as_float(p.y));
    }
    float4 o0 = make_float4(acc[0], acc[1], acc[2], acc[3]);
    float4 o1 = make_float4(acc[4], acc[5], acc[6], acc[7]);
    *(float4*)&out[row * C + lane * 8] = o0;
    *(float4*)&out[row * C + lane * 8 + 4] = o1;
}

// ---------------- BN statistics ----------------
__global__ __launch_bounds__(256) void bn_stats_kernel(const float* __restrict__ H,
                                                       float* __restrict__ sum,
                                                       float* __restrict__ sumsq) {
    int c = threadIdx.x & 127;
    int half = threadIdx.x >> 7;
    float s = 0.f, q = 0.f;
    for (int r = blockIdx.x * 2 + half; r < N_NODES; r += 512) {
        float v = H[r * 128 + c];
        s += v;
        q += v * v;
    }
    __shared__ float ls[256], lq[256];
    ls[threadIdx.x] = s;
    lq[threadIdx.x] = q;
    __syncthreads();
    if (half == 0) {
        atomicAdd(&sum[c], ls[c] + ls[c + 128]);
        atomicAdd(&sumsq[c], lq[c] + lq[c + 128]);
    }
}

__global__ void bn_finalize_kernel(const float* __restrict__ sum,
                                   const float* __restrict__ sumsq,
                                   const float* __restrict__ gamma,
                                   const float* __restrict__ beta,
                                   float* __restrict__ scale,
                                   float* __restrict__ shift) {
    int c = threadIdx.x;
    if (c < 128) {
        float mean = sum[c] * (1.0f / N_NODES);
        float var = sumsq[c] * (1.0f / N_NODES) - mean * mean;
        float sc = gamma[c] * rsqrtf(var + BN_EPS);
        scale[c] = sc;
        shift[c] = beta[c] - mean * sc;
    }
}

extern "C" void kernel_launch(void* const* d_in, const int* in_sizes, int n_in,
                              void* d_out, int out_size, void* d_ws, size_t ws_size,
                              hipStream_t stream) {
    const float* x     = (const float*)d_in[0];
    const int*   ei    = (const int*)d_in[1];
    const float* W1    = (const float*)d_in[2];
    const float* b1    = (const float*)d_in[3];
    const float* gamma = (const float*)d_in[4];
    const float* beta  = (const float*)d_in[5];
    const float* W2    = (const float*)d_in[6];
    const float* b2    = (const float*)d_in[7];
    float* out = (float*)d_out;
    const int* src = ei;
    const int* dst = ei + N_EDGES;

    // ---- workspace layout (4-byte words) ----
    // 0          dinv    [50176]
    // 50176      stats   [512]
    // 50688      psum    [128]
    // 50816      rowcnt  [50176]
    // 100992     rowptr  [50176]
    // 151168     BIG:
    //   h1bf  @ BIG+0        [3,200,000]   (alias: part_cnt/part_deg/cursor, dead by gemm1)
    //   h1agg @ BIG+3.2M     [6,400,000]
    //   epair @ BIG+9.6M     [1,600,000]
    // total 11,351,168 words = 45.4 MB
    float* ws     = (float*)d_ws;
    float* dinv   = ws;
    float* stats  = ws + NPAD;
    int*   psum   = (int*)(ws + NPAD + 512);
    int*   rowcnt = psum + 128;
    int*   rowptr = rowcnt + NPAD;
    float* big    = (float*)(rowptr + NPAD);
    // CSR-build aliases inside BIG (dead before gemm1 writes h1bf / spmm1 writes h1agg):
    ushort* part_cnt = (ushort*)big;                         // S*NP7 ushorts = 917,504 w
    ushort* part_deg = part_cnt + S_SLICES * NP7;            // 917,504 w  -> ends 1,835,008
    int*    cursor   = (int*)(part_deg + S_SLICES * NP7);    // S*NP7 ints = 1,835,008 w -> ends 3,670,016
    // persistent tensors:
    uint*  h1bf   = (uint*)big;                              // N*64 uints (bf16 x128)
    float* h1agg  = big + 3200000;                           // N*128 fp32
    int2*  epair  = (int2*)(big + 9600000);                  // N_EDGES pairs
    uint*  h2bf   = h1bf;                                    // alias (h1bf dead after spmm1)
    float* sum    = stats;
    float* sumsq  = stats + 128;
    float* scale  = stats + 256;
    float* shift  = stats + 384;

    hipMemsetAsync(stats, 0, 512 * sizeof(float), stream);

    count_hist_kernel<<<S_SLICES * R_RANGES, 256, 0, stream>>>(src, dst, part_cnt, part_deg);
    dinv_rowcnt_kernel<<<NPAD / 512, 256, 0, stream>>>(part_deg, part_cnt, dinv, rowcnt);

    scan1_kernel<<<SCAN_BLOCKS, 512, 0, stream>>>(rowcnt, rowptr, psum);
    scan2_kernel<<<1, 64, 0, stream>>>(psum);
    scan3_kernel<<<SCAN_BLOCKS, 512, 0, stream>>>(rowcnt, rowptr, psum);
    cursor_init_kernel<<<NPAD / 512, 256, 0, stream>>>(rowptr, part_cnt, cursor);
    fill_lds_kernel<<<S_SLICES * R_RANGES, 256, 0, stream>>>(src, dst, dinv, cursor, epair);

    gemm1_kernel<<<(N_NODES + 127) / 128, 256, 0, stream>>>(x, W1, b1, h1bf);

    spmm_bf16_kernel<128><<<(N_NODES + 15) / 16, 256, 0, stream>>>(rowptr, epair, dinv, h1bf, h1agg);

    bn_stats_kernel<<<256, 256, 0, stream>>>(h1agg, sum, sumsq);
    bn_finalize_kernel<<<1, 128, 0, stream>>>(sum, sumsq, gamma, beta, scale, shift);

    gemm2_kernel<<<(N_NODES + 127) / 128, 256, 0, stream>>>(h1agg, W2, b2, scale, shift, h2bf);

    spmm_bf16_kernel<64><<<(N_NODES + 31) / 32, 256, 0, stream>>>(rowptr, epair, dinv, h2bf, out);
}

// Round 6
// 277.448 us; speedup vs baseline: 2.6991x; 1.0655x over previous
//
#include <hip/hip_runtime.h>

#define N_NODES 50000
#define N_EDGES 800000
#define BN_EPS 1e-5f
#define NPAD 50176          // N_NODES padded to 98*512
#define SCAN_BLOCKS 98      // 98*512 = 50176

// CSR-build tiling: 64 edge slices x 7 node ranges of 8192 bins
#define S_SLICES 64
#define R_RANGES 7
#define BINS 8192
#define NP7 (R_RANGES * BINS)        // 57344 bins per slice (covers NPAD)
#define ES (N_EDGES / S_SLICES)      // 12500 edges per slice

#define XS_STRIDE 68                 // LDS row stride in uints (136 bf16): bank spread

typedef unsigned int uint;
typedef unsigned short ushort;
typedef float floatx4 __attribute__((ext_vector_type(4)));
typedef short bf16x8 __attribute__((ext_vector_type(8)));

// ---- bf16 helpers (stored as packed pairs in uint / scalar ushort) ----
__device__ __forceinline__ float bfl(uint u) { return __uint_as_float(u << 16); }
__device__ __forceinline__ float bfh(uint u) { return __uint_as_float(u & 0xffff0000u); }
__device__ __forceinline__ uint pack_bf2(float a, float b) {
    uint ua = __float_as_uint(a), ub = __float_as_uint(b);
    ua += 0x7fffu + ((ua >> 16) & 1u);   // RNE
    ub += 0x7fffu + ((ub >> 16) & 1u);
    return (ua >> 16) | (ub & 0xffff0000u);
}
__device__ __forceinline__ ushort bf1(float x) {
    uint u = __float_as_uint(x);
    u += 0x7fffu + ((u >> 16) & 1u);
    return (ushort)(u >> 16);
}
__device__ __forceinline__ void acc8(float* a, uint4 h, float w) {
    a[0] += w * bfl(h.x); a[1] += w * bfh(h.x);
    a[2] += w * bfl(h.y); a[3] += w * bfh(h.y);
    a[4] += w * bfl(h.z); a[5] += w * bfh(h.z);
    a[6] += w * bfl(h.w); a[7] += w * bfh(h.w);
}

// ---------------- weight prep: W1[k][n]->W1t bf16[n][k], W2 likewise ----------------
__global__ __launch_bounds__(256) void prep_w_kernel(const float* __restrict__ W1,
                                                     const float* __restrict__ W2,
                                                     uint* __restrict__ W1t,
                                                     uint* __restrict__ W2t) {
    int t = blockIdx.x * 256 + threadIdx.x;
    if (t < 8192) {
        int n = t >> 6, kk = t & 63;
        W1t[t] = pack_bf2(W1[(2 * kk) * 128 + n], W1[(2 * kk + 1) * 128 + n]);
    } else if (t < 12288) {
        int u = t - 8192;
        int n = u >> 6, kk = u & 63;
        W2t[u] = pack_bf2(W2[(2 * kk) * 64 + n], W2[(2 * kk + 1) * 64 + n]);
    }
}

// ---------------- count: LDS histograms per (slice, range), plain-store partials ----
__global__ __launch_bounds__(256) void count_hist_kernel(const int* __restrict__ src,
                                                         const int* __restrict__ dst,
                                                         ushort* __restrict__ part_cnt,
                                                         ushort* __restrict__ part_deg) {
    __shared__ uint cnt_lds[BINS];
    __shared__ uint deg_lds[BINS];
    const int s = blockIdx.x / R_RANGES;
    const int r = blockIdx.x % R_RANGES;
    const int base = r * BINS;
    for (int j = threadIdx.x; j < BINS; j += 256) { cnt_lds[j] = 0u; deg_lds[j] = 0u; }
    __syncthreads();
    const int e0 = s * ES;
    for (int i = threadIdx.x; i < ES; i += 256) {
        int e = e0 + i;
        int ss = src[e], dd = dst[e];
        if (ss != dd) {
            int a = ss - base;
            if ((unsigned)a < (unsigned)BINS) atomicAdd(&cnt_lds[a], 1u);
            int b = dd - base;
            if ((unsigned)b < (unsigned)BINS) atomicAdd(&deg_lds[b], 1u);
        }
    }
    __syncthreads();
    uint* pc = (uint*)&part_cnt[s * NP7 + base];
    uint* pd = (uint*)&part_deg[s * NP7 + base];
    for (int j = threadIdx.x; j < BINS / 2; j += 256) {
        pc[j] = (cnt_lds[2 * j] & 0xffffu) | (cnt_lds[2 * j + 1] << 16);
        pd[j] = (deg_lds[2 * j] & 0xffffu) | (deg_lds[2 * j + 1] << 16);
    }
}

// ---------------- reduce partials: dinv + total rowcnt (2 nodes/thread) ----------------
__global__ __launch_bounds__(256) void dinv_rowcnt_kernel(const ushort* __restrict__ part_deg,
                                                          const ushort* __restrict__ part_cnt,
                                                          float* __restrict__ dinv,
                                                          int* __restrict__ rowcnt) {
    int i = (blockIdx.x * 256 + threadIdx.x) * 2;   // i < NPAD, even
    uint dg0 = 0, dg1 = 0, rc0 = 0, rc1 = 0;
#pragma unroll 8
    for (int s = 0; s < S_SLICES; ++s) {
        uint vd = *(const uint*)&part_deg[s * NP7 + i];
        uint vc = *(const uint*)&part_cnt[s * NP7 + i];
        dg0 += vd & 0xffffu; dg1 += vd >> 16;
        rc0 += vc & 0xffffu; rc1 += vc >> 16;
    }
    *(int2*)&rowcnt[i] = make_int2((int)rc0, (int)rc1);
    if (i < N_NODES) dinv[i] = rsqrtf((float)dg0 + 1.0f);
    if (i + 1 < N_NODES) dinv[i + 1] = rsqrtf((float)dg1 + 1.0f);
}

// ---------------- exclusive scan of rowcnt -> rowptr ----------------
__global__ __launch_bounds__(512) void scan1_kernel(const int* __restrict__ rowcnt,
                                                    int* __restrict__ rowptr,
                                                    int* __restrict__ psum) {
    __shared__ int buf[512];
    int t = threadIdx.x;
    int g = blockIdx.x * 512 + t;
    buf[t] = rowcnt[g];
    __syncthreads();
#pragma unroll
    for (int off = 1; off < 512; off <<= 1) {
        int x = (t >= off) ? buf[t - off] : 0;
        __syncthreads();
        buf[t] += x;
        __syncthreads();
    }
    rowptr[g] = buf[t];
    if (t == 511) psum[blockIdx.x] = buf[511];
}

__global__ void scan2_kernel(int* __restrict__ psum) {
    if (threadIdx.x == 0) {
        int acc = 0;
        for (int i = 0; i < SCAN_BLOCKS; ++i) {
            int v = psum[i];
            psum[i] = acc;
            acc += v;
        }
    }
}

__global__ __launch_bounds__(512) void scan3_kernel(const int* __restrict__ rowcnt,
                                                    int* __restrict__ rowptr,
                                                    const int* __restrict__ psum) {
    int t = threadIdx.x;
    int g = blockIdx.x * 512 + t;
    rowptr[g] = rowptr[g] - rowcnt[g] + psum[blockIdx.x];
}

// ---------------- per-(slice,node) cursor bases (2 nodes/thread) ----------------
__global__ __launch_bounds__(256) void cursor_init_kernel(const int* __restrict__ rowptr,
                                                          const ushort* __restrict__ part_cnt,
                                                          int* __restrict__ cursor) {
    int i = (blockIdx.x * 256 + threadIdx.x) * 2;   // i < NPAD, even
    int b0 = rowptr[i], b1 = rowptr[i + 1];
#pragma unroll 8
    for (int s = 0; s < S_SLICES; ++s) {
        *(int2*)&cursor[s * NP7 + i] = make_int2(b0, b1);
        uint vc = *(const uint*)&part_cnt[s * NP7 + i];
        b0 += (int)(vc & 0xffffu);
        b1 += (int)(vc >> 16);
    }
}

// ---------------- fill CSR via LDS cursors: (col, weight) pairs ----------------
__global__ __launch_bounds__(256) void fill_lds_kernel(const int* __restrict__ src,
                                                       const int* __restrict__ dst,
                                                       const float* __restrict__ dinv,
                                                       const int* __restrict__ cursor,
                                                       int2* __restrict__ epair) {
    __shared__ int curs[BINS];
    const int s = blockIdx.x / R_RANGES;
    const int r = blockIdx.x % R_RANGES;
    const int base = r * BINS;
    const int* gc = &cursor[s * NP7 + base];
    for (int j = threadIdx.x; j < BINS; j += 256) curs[j] = gc[j];
    __syncthreads();
    const int e0 = s * ES;
    for (int i = threadIdx.x; i < ES; i += 256) {
        int e = e0 + i;
        int ss = src[e], dd = dst[e];
        int a = ss - base;
        if (ss != dd && (unsigned)a < (unsigned)BINS) {
            int pos = atomicAdd(&curs[a], 1);
            epair[pos] = make_int2(dd, __float_as_int(dinv[ss] * dinv[dd]));
        }
    }
}

// ---------------- GEMM1 (MFMA): Hbf = bf16(X @ W1 + b1), 64-row tiles ----------------
__global__ __launch_bounds__(256) void gemm1_mfma_kernel(const float* __restrict__ X,
                                                         const uint* __restrict__ W1t,
                                                         const float* __restrict__ bias,
                                                         ushort* __restrict__ Hbf) {
    __shared__ uint lds[(64 + 128) * XS_STRIDE];   // Xs(64 rows) + Ws(128 n-rows), 52 KB
    uint* Xs = lds;
    uint* Ws = lds + 64 * XS_STRIDE;
    const int t = threadIdx.x;
    const int rowBase = blockIdx.x * 64;

    // stage X tile: 64 rows x 128 fp32 -> bf16 pairs (zero OOB rows)
    {
        int r = t >> 2, q = t & 3;
        int arow = rowBase + r;
        uint* xd = &Xs[r * XS_STRIDE + q * 16];
        if (arow < N_NODES) {
            const float4* xp = (const float4*)&X[arow * 128 + q * 32];
#pragma unroll
            for (int i = 0; i < 8; ++i) {
                float4 v = xp[i];
                xd[2 * i]     = pack_bf2(v.x, v.y);
                xd[2 * i + 1] = pack_bf2(v.z, v.w);
            }
        } else {
#pragma unroll
            for (int i = 0; i < 16; ++i) xd[i] = 0u;
        }
    }
    // stage W1t: 128 n-rows x 64 uints
    {
        int n = t >> 1, half = t & 1;
        const uint4* wp = (const uint4*)&W1t[n * 64 + half * 32];
        uint* wd = &Ws[n * XS_STRIDE + half * 32];
#pragma unroll
        for (int i = 0; i < 8; ++i) *(uint4*)&wd[i * 4] = wp[i];
    }
    __syncthreads();

    const int wv = t >> 6, lane = t & 63;
    const int lr = lane & 15;
    const int ko = (lane >> 4) * 4;    // uint offset of lane's 8-bf16 chunk within 32-k
    const int m0 = wv * 16;
    floatx4 acc[8];
#pragma unroll
    for (int j = 0; j < 8; ++j) acc[j] = (floatx4){0.f, 0.f, 0.f, 0.f};

#pragma unroll
    for (int ks = 0; ks < 4; ++ks) {
        const int kb = ks * 16 + ko;
        bf16x8 a = *(bf16x8*)&Xs[(m0 + lr) * XS_STRIDE + kb];
#pragma unroll
        for (int j = 0; j < 8; ++j) {
            bf16x8 b = *(bf16x8*)&Ws[(j * 16 + lr) * XS_STRIDE + kb];
            acc[j] = __builtin_amdgcn_mfma_f32_16x16x32_bf16(a, b, acc[j], 0, 0, 0);
        }
    }
    // epilogue: C/D col=lane&15, row=(lane>>4)*4+reg; direct bf16 stores
    const int rbase = rowBase + m0 + (lane >> 4) * 4;
#pragma unroll
    for (int j = 0; j < 8; ++j) {
        const int col = j * 16 + lr;
        const float bb = bias[col];
#pragma unroll
        for (int r = 0; r < 4; ++r) {
            int row = rbase + r;
            if (row < N_NODES) Hbf[row * 128 + col] = bf1(acc[j][r] + bb);
        }
    }
}

// ---------------- GEMM2 (MFMA): Hbf = bf16(relu(bn(Hin)) @ W2 + b2) ----------------
__global__ __launch_bounds__(256) void gemm2_mfma_kernel(const float* __restrict__ Hin,
                                                         const uint* __restrict__ W2t,
                                                         const float* __restrict__ bias,
                                                         const float* __restrict__ scale,
                                                         const float* __restrict__ shift,
                                                         ushort* __restrict__ Hbf) {
    __shared__ uint lds[(64 + 64) * XS_STRIDE];    // Xs(64 rows) + Ws(64 n-rows), 35 KB
    uint* Xs = lds;
    uint* Ws = lds + 64 * XS_STRIDE;
    const int t = threadIdx.x;
    const int rowBase = blockIdx.x * 64;

    // stage A tile with fused BN+ReLU -> bf16
    {
        int r = t >> 2, q = t & 3;
        int arow = rowBase + r;
        uint* xd = &Xs[r * XS_STRIDE + q * 16];
        if (arow < N_NODES) {
            const float4* xp  = (const float4*)&Hin[arow * 128 + q * 32];
            const float4* sc4 = (const float4*)&scale[q * 32];
            const float4* sh4 = (const float4*)&shift[q * 32];
#pragma unroll
            for (int i = 0; i < 8; ++i) {
                float4 v = xp[i], sc = sc4[i], sh = sh4[i];
                float a0 = fmaxf(0.f, v.x * sc.x + sh.x);
                float a1 = fmaxf(0.f, v.y * sc.y + sh.y);
                float a2 = fmaxf(0.f, v.z * sc.z + sh.z);
                float a3 = fmaxf(0.f, v.w * sc.w + sh.w);
                xd[2 * i]     = pack_bf2(a0, a1);
                xd[2 * i + 1] = pack_bf2(a2, a3);
            }
        } else {
#pragma unroll
            for (int i = 0; i < 16; ++i) xd[i] = 0u;
        }
    }
    // stage W2t: 64 n-rows x 64 uints (threads 0..127)
    if (t < 128) {
        int n = t >> 1, half = t & 1;
        const uint4* wp = (const uint4*)&W2t[n * 64 + half * 32];
        uint* wd = &Ws[n * XS_STRIDE + half * 32];
#pragma unroll
        for (int i = 0; i < 8; ++i) *(uint4*)&wd[i * 4] = wp[i];
    }
    __syncthreads();

    const int wv = t >> 6, lane = t & 63;
    const int lr = lane & 15;
    const int ko = (lane >> 4) * 4;
    const int m0 = wv * 16;
    floatx4 acc[4];
#pragma unroll
    for (int j = 0; j < 4; ++j) acc[j] = (floatx4){0.f, 0.f, 0.f, 0.f};

#pragma unroll
    for (int ks = 0; ks < 4; ++ks) {
        const int kb = ks * 16 + ko;
        bf16x8 a = *(bf16x8*)&Xs[(m0 + lr) * XS_STRIDE + kb];
#pragma unroll
        for (int j = 0; j < 4; ++j) {
            bf16x8 b = *(bf16x8*)&Ws[(j * 16 + lr) * XS_STRIDE + kb];
            acc[j] = __builtin_amdgcn_mfma_f32_16x16x32_bf16(a, b, acc[j], 0, 0, 0);
        }
    }
    const int rbase = rowBase + m0 + (lane >> 4) * 4;
#pragma unroll
    for (int j = 0; j < 4; ++j) {
        const int col = j * 16 + lr;
        const float bb = bias[col];
#pragma unroll
        for (int r = 0; r < 4; ++r) {
            int row = rbase + r;
            if (row < N_NODES) Hbf[row * 64 + col] = bf1(acc[j][r] + bb);
        }
    }
}

// ---------------- CSR gather SpMM over bf16 H, fp32 accumulate ----------------
template <int C>
__global__ __launch_bounds__(256) void spmm_bf16_kernel(const int* __restrict__ rowptr,
                                                        const int2* __restrict__ epair,
                                                        const float* __restrict__ dinv,
                                                        const uint* __restrict__ H,
                                                        float* __restrict__ out) {
    constexpr int LPR = C / 8;        // lanes per row
    constexpr int RPB = 256 / LPR;    // rows per block
    constexpr int US  = C / 2;        // uint row stride
    const int t = threadIdx.x;
    const int lane = t % LPR;
    const int row = blockIdx.x * RPB + t / LPR;
    if (row >= N_NODES) return;
    const int cu = lane * 4;          // uint offset (8 channels)
    const float di = dinv[row];

    float acc[8];
    {
        uint4 hv = *(const uint4*)&H[row * US + cu];
        float w = di * di;
        acc[0] = w * bfl(hv.x); acc[1] = w * bfh(hv.x);
        acc[2] = w * bfl(hv.y); acc[3] = w * bfh(hv.y);
        acc[4] = w * bfl(hv.z); acc[5] = w * bfh(hv.z);
        acc[6] = w * bfl(hv.w); acc[7] = w * bfh(hv.w);
    }
    const int e0 = rowptr[row], e1 = rowptr[row + 1];
    int e = e0;
    for (; e + 4 <= e1; e += 4) {
        int2 p0 = epair[e + 0], p1 = epair[e + 1], p2 = epair[e + 2], p3 = epair[e + 3];
        uint4 h0 = *(const uint4*)&H[p0.x * US + cu];
        uint4 h1 = *(const uint4*)&H[p1.x * US + cu];
        uint4 h2 = *(const uint4*)&H[p2.x * US + cu];
        uint4 h3 = *(const uint4*)&H[p3.x * US + cu];
        acc8(acc, h0, __int_as_float(p0.y));
        acc8(acc, h1, __int_as_float(p1.y));
        acc8(acc, h2, __int_as_float(p2.y));
        acc8(acc, h3, __int_as_float(p3.y));
    }
    for (; e < e1; ++e) {
        int2 p = epair[e];
        uint4 h = *(const uint4*)&H[p.x * US + cu];
        acc8(acc, h, __int_as_float(p.y));
    }
    float4 o0 = make_float4(acc[0], acc[1], acc[2], acc[3]);
    float4 o1 = make_float4(acc[4], acc[5], acc[6], acc[7]);
    *(float4*)&out[row * C + lane * 8] = o0;
    *(float4*)&out[row * C + lane * 8 + 4] = o1;
}

// ---------------- BN statistics ----------------
__global__ __launch_bounds__(256) void bn_stats_kernel(const float* __restrict__ H,
                                                       float* __restrict__ sum,
                                                       float* __restrict__ sumsq) {
    int c = threadIdx.x & 127;
    int half = threadIdx.x >> 7;
    float s = 0.f, q = 0.f;
    for (int r = blockIdx.x * 2 + half; r < N_NODES; r += 512) {
        float v = H[r * 128 + c];
        s += v;
        q += v * v;
    }
    __shared__ float ls[256], lq[256];
    ls[threadIdx.x] = s;
    lq[threadIdx.x] = q;
    __syncthreads();
    if (half == 0) {
        atomicAdd(&sum[c], ls[c] + ls[c + 128]);
        atomicAdd(&sumsq[c], lq[c] + lq[c + 128]);
    }
}

__global__ void bn_finalize_kernel(const float* __restrict__ sum,
                                   const float* __restrict__ sumsq,
                                   const float* __restrict__ gamma,
                                   const float* __restrict__ beta,
                                   float* __restrict__ scale,
                                   float* __restrict__ shift) {
    int c = threadIdx.x;
    if (c < 128) {
        float mean = sum[c] * (1.0f / N_NODES);
        float var = sumsq[c] * (1.0f / N_NODES) - mean * mean;
        float sc = gamma[c] * rsqrtf(var + BN_EPS);
        scale[c] = sc;
        shift[c] = beta[c] - mean * sc;
    }
}

extern "C" void kernel_launch(void* const* d_in, const int* in_sizes, int n_in,
                              void* d_out, int out_size, void* d_ws, size_t ws_size,
                              hipStream_t stream) {
    const float* x     = (const float*)d_in[0];
    const int*   ei    = (const int*)d_in[1];
    const float* W1    = (const float*)d_in[2];
    const float* b1    = (const float*)d_in[3];
    const float* gamma = (const float*)d_in[4];
    const float* beta  = (const float*)d_in[5];
    const float* W2    = (const float*)d_in[6];
    const float* b2    = (const float*)d_in[7];
    float* out = (float*)d_out;
    const int* src = ei;
    const int* dst = ei + N_EDGES;

    // ---- workspace layout (4-byte words) ----
    float* ws     = (float*)d_ws;
    float* dinv   = ws;                          // NPAD
    float* stats  = ws + NPAD;                   // 512
    int*   psum   = (int*)(ws + NPAD + 512);     // 128
    int*   rowcnt = psum + 128;                  // NPAD
    int*   rowptr = rowcnt + NPAD;               // NPAD
    float* big    = (float*)(rowptr + NPAD);
    // CSR-build aliases inside BIG (dead before gemm1 writes h1bf):
    ushort* part_cnt = (ushort*)big;                         // S*NP7 ushorts
    ushort* part_deg = part_cnt + S_SLICES * NP7;
    int*    cursor   = (int*)(part_deg + S_SLICES * NP7);    // S*NP7 ints
    // persistent tensors:
    ushort* h1bf  = (ushort*)big;                            // N*128 bf16
    float*  h1agg = big + 3200000;                           // N*128 fp32
    int2*   epair = (int2*)(big + 9600000);                  // N_EDGES pairs
    uint*   W1t   = (uint*)(big + 11200000);                 // 8192 uints
    uint*   W2t   = W1t + 8192;                              // 4096 uints
    ushort* h2bf  = h1bf;                                    // alias (h1bf dead after spmm1)
    float* sum    = stats;
    float* sumsq  = stats + 128;
    float* scale  = stats + 256;
    float* shift  = stats + 384;

    hipMemsetAsync(stats, 0, 512 * sizeof(float), stream);

    prep_w_kernel<<<48, 256, 0, stream>>>(W1, W2, W1t, W2t);

    count_hist_kernel<<<S_SLICES * R_RANGES, 256, 0, stream>>>(src, dst, part_cnt, part_deg);
    dinv_rowcnt_kernel<<<NPAD / 512, 256, 0, stream>>>(part_deg, part_cnt, dinv, rowcnt);

    scan1_kernel<<<SCAN_BLOCKS, 512, 0, stream>>>(rowcnt, rowptr, psum);
    scan2_kernel<<<1, 64, 0, stream>>>(psum);
    scan3_kernel<<<SCAN_BLOCKS, 512, 0, stream>>>(rowcnt, rowptr, psum);
    cursor_init_kernel<<<NPAD / 512, 256, 0, stream>>>(rowptr, part_cnt, cursor);
    fill_lds_kernel<<<S_SLICES * R_RANGES, 256, 0, stream>>>(src, dst, dinv, cursor, epair);

    gemm1_mfma_kernel<<<(N_NODES + 63) / 64, 256, 0, stream>>>(x, W1t, b1, h1bf);

    spmm_bf16_kernel<128><<<(N_NODES + 15) / 16, 256, 0, stream>>>(rowptr, epair, dinv,
                                                                   (const uint*)h1bf, h1agg);

    bn_stats_kernel<<<256, 256, 0, stream>>>(h1agg, sum, sumsq);
    bn_finalize_kernel<<<1, 128, 0, stream>>>(sum, sumsq, gamma, beta, scale, shift);

    gemm2_mfma_kernel<<<(N_NODES + 63) / 64, 256, 0, stream>>>(h1agg, W2t, b2, scale, shift, h2bf);

    spmm_bf16_kernel<64><<<(N_NODES + 31) / 32, 256, 0, stream>>>(rowptr, epair, dinv,
                                                                  (const uint*)h2bf, out);
}